// Round 1
// baseline (422.555 us; speedup 1.0000x reference)
//
#include <hip/hip_runtime.h>
#include <hip/hip_bf16.h>

// WindowAttention fused kernel for MI355X (gfx950).
// Design (round 1, correctness-first):
//  - prep kernel: W_qkv (384x1152) and W_proj (384x384) -> transposed f16 [n][k] in d_ws.
//  - main kernel: 1 block per (batch, window) = 1024 blocks, 256 threads (4 waves).
//    Per block: stage x window (64x384) f32->f16 in LDS; loop 12 heads:
//      QKV head GEMM (64x384 @ 384x96) via mfma_f32_16x16x32_f16,
//      softmax in-register (16-lane shfl_xor groups), PV MFMA; accumulate attention
//      output tile (64x384 f16) in LDS; then fused proj GEMM (64x384 @ 384x384),
//      fp32 output written with window->token un-permutation.
// Fragment layouts (learn_hip m89/m91 verified): A row-major [m][k], B as B^T rows
// [n][k], 16B/lane; C/D: col=lane&15, row=(lane>>4)*4+reg.

typedef _Float16 f16;
typedef f16 f16x8 __attribute__((ext_vector_type(8)));
typedef f16 f16x4 __attribute__((ext_vector_type(4)));
typedef float f32x4 __attribute__((ext_vector_type(4)));

#define MFMA_F16(a, b, c) __builtin_amdgcn_mfma_f32_16x16x32_f16((a), (b), (c), 0, 0, 0)

namespace {
constexpr int kC = 384;
constexpr int kNH = 12;
constexpr int kHD = 32;
constexpr int kNTok = 4096;
constexpr float kScale = 0.17677669529663687f;  // 1/sqrt(32)
constexpr int kWtQkvElems = 3 * kC * kC;        // 442368
constexpr int kWpElems = kC * kC;               // 147456
}

// ---- weight prep: transpose + f32->f16 ----
__global__ void prep_weights(const float* __restrict__ Wqkv,
                             const float* __restrict__ Wproj,
                             f16* __restrict__ wt_qkv,   // [1152][384]
                             f16* __restrict__ wp_t) {   // [384][384]
  int i = blockIdx.x * 256 + threadIdx.x;
  if (i < kWtQkvElems) {
    int n = i % (3 * kC);           // coalesced read along n
    int k = i / (3 * kC);
    wt_qkv[(size_t)n * kC + k] = (f16)Wqkv[(size_t)k * (3 * kC) + n];
  } else {
    int j = i - kWtQkvElems;
    if (j < kWpElems) {
      int n = j % kC;
      int k = j / kC;
      wp_t[(size_t)n * kC + k] = (f16)Wproj[(size_t)k * kC + n];
    }
  }
}

__global__ __launch_bounds__(256, 1) void win_attn_fused(
    const float* __restrict__ x,
    const float* __restrict__ b_qkv,
    const f16* __restrict__ wt_qkv,
    const f16* __restrict__ wp_t,
    float* __restrict__ out) {
  // LDS: 50176 + 50176 + 5120 + 5120 + 4608 + 9216 = 124416 B (<160 KiB)
  __shared__ alignas(16) f16 xs[64][392];      // x window, pad +8 (2-way banks)
  __shared__ alignas(16) f16 ao[64][392];      // attention output tile
  __shared__ alignas(16) f16 q_s[64][40];      // q head tile [t][d]
  __shared__ alignas(16) f16 k_s[64][40];      // k head tile [t][d]
  __shared__ alignas(16) f16 vT[32][72];       // v head tile transposed [d][t]
  __shared__ alignas(16) f16 p_s[4][16][72];   // per-wave P tile [r][c]

  const int tid = threadIdx.x;
  const int wid = tid >> 6;
  const int lane = tid & 63;
  const int g = lane >> 4;        // 0..3
  const int l15 = lane & 15;
  const int wm = wid >> 1;        // wave row-half (QKV/proj)
  const int wn = wid & 1;         // wave col-half

  const int blk = blockIdx.x;
  const int b = blk >> 6;
  const int win = blk & 63;
  const int wh = win >> 3;
  const int ww = win & 7;

  const f32x4 zero4 = {0.f, 0.f, 0.f, 0.f};

  // ---- stage x window: 64 rows x 384 cols, f32 -> f16 ----
  {
    const float* xb = x + (size_t)b * kNTok * kC;
    #pragma unroll
    for (int it = 0; it < 24; ++it) {
      int idx = tid + it * 256;          // 0..6143 over 64 rows x 96 float4
      int r = idx / 96;
      int c4 = idx - r * 96;
      int n = (wh * 8 + (r >> 3)) * 64 + ww * 8 + (r & 7);
      float4 v = *reinterpret_cast<const float4*>(xb + (size_t)n * kC + c4 * 4);
      f16x4 hv = {(f16)v.x, (f16)v.y, (f16)v.z, (f16)v.w};
      *reinterpret_cast<f16x4*>(&xs[r][c4 * 4]) = hv;
    }
  }
  __syncthreads();

  for (int h = 0; h < kNH; ++h) {
    // ---- QKV head GEMM: qkv(64x96) = xs(64x384) @ W_head(384x96) ----
    // wave (wm,wn): rows 32*wm..+32 (2 m-tiles), cols 48*wn..+48 (3 n-tiles)
    f32x4 acc[2][3];
    #pragma unroll
    for (int mt = 0; mt < 2; ++mt)
      #pragma unroll
      for (int nt = 0; nt < 3; ++nt) acc[mt][nt] = zero4;

    #pragma unroll 2
    for (int ks = 0; ks < 12; ++ks) {
      f16x8 af[2];
      #pragma unroll
      for (int mt = 0; mt < 2; ++mt)
        af[mt] = *reinterpret_cast<const f16x8*>(
            &xs[wm * 32 + mt * 16 + l15][ks * 32 + g * 8]);
      f16x8 bf[3];
      #pragma unroll
      for (int nt = 0; nt < 3; ++nt) {
        int nl = wn * 48 + nt * 16 + l15;                 // 0..95
        int grow = (nl >> 5) * kC + h * kHD + (nl & 31);  // row in wt_qkv
        bf[nt] = *reinterpret_cast<const f16x8*>(
            &wt_qkv[(size_t)grow * kC + ks * 32 + g * 8]);
      }
      #pragma unroll
      for (int mt = 0; mt < 2; ++mt)
        #pragma unroll
        for (int nt = 0; nt < 3; ++nt)
          acc[mt][nt] = MFMA_F16(af[mt], bf[nt], acc[mt][nt]);
    }

    // scatter q/k/v head tiles to LDS (+bias)
    #pragma unroll
    for (int nt = 0; nt < 3; ++nt) {
      int nl = wn * 48 + nt * 16 + l15;
      int sec = nl >> 5;        // uniform within a 16-wide tile
      int col = nl & 31;
      float bias = b_qkv[sec * kC + h * kHD + col];
      #pragma unroll
      for (int mt = 0; mt < 2; ++mt) {
        #pragma unroll
        for (int j = 0; j < 4; ++j) {
          int r = wm * 32 + mt * 16 + g * 4 + j;
          f16 hv = (f16)(acc[mt][nt][j] + bias);
          if (sec == 0) q_s[r][col] = hv;
          else if (sec == 1) k_s[r][col] = hv;
          else vT[col][r] = hv;
        }
      }
    }
    __syncthreads();

    // ---- S = q @ k^T * scale ; wave wid owns rows 16*wid..+16, all 64 cols ----
    f32x4 sacc[4];
    #pragma unroll
    for (int nt = 0; nt < 4; ++nt) sacc[nt] = zero4;
    f16x8 qa =
        *reinterpret_cast<const f16x8*>(&q_s[wid * 16 + l15][g * 8]);
    #pragma unroll
    for (int nt = 0; nt < 4; ++nt) {
      f16x8 kb = *reinterpret_cast<const f16x8*>(&k_s[nt * 16 + l15][g * 8]);
      sacc[nt] = MFMA_F16(qa, kb, sacc[nt]);
    }

    // softmax per row; row r=4g+j lives in the 16 lanes of group g
    float pv[4][4];
    #pragma unroll
    for (int j = 0; j < 4; ++j) {
      float m = -1e30f;
      #pragma unroll
      for (int nt = 0; nt < 4; ++nt) {
        pv[nt][j] = sacc[nt][j] * kScale;
        m = fmaxf(m, pv[nt][j]);
      }
      m = fmaxf(m, __shfl_xor(m, 1));
      m = fmaxf(m, __shfl_xor(m, 2));
      m = fmaxf(m, __shfl_xor(m, 4));
      m = fmaxf(m, __shfl_xor(m, 8));
      float s = 0.f;
      #pragma unroll
      for (int nt = 0; nt < 4; ++nt) {
        pv[nt][j] = __expf(pv[nt][j] - m);
        s += pv[nt][j];
      }
      s += __shfl_xor(s, 1);
      s += __shfl_xor(s, 2);
      s += __shfl_xor(s, 4);
      s += __shfl_xor(s, 8);
      float inv = 1.0f / s;
      #pragma unroll
      for (int nt = 0; nt < 4; ++nt)
        p_s[wid][g * 4 + j][nt * 16 + l15] = (f16)(pv[nt][j] * inv);
    }
    __syncthreads();  // conservative: order p_s writes before PV reads

    // ---- O = P @ V : wave rows 16, cols 32, K=64 (2 k-steps) ----
    f32x4 oacc[2];
    oacc[0] = zero4;
    oacc[1] = zero4;
    #pragma unroll
    for (int ks = 0; ks < 2; ++ks) {
      f16x8 pa = *reinterpret_cast<const f16x8*>(
          &p_s[wid][l15][ks * 32 + g * 8]);
      #pragma unroll
      for (int nt = 0; nt < 2; ++nt) {
        f16x8 vb = *reinterpret_cast<const f16x8*>(
            &vT[nt * 16 + l15][ks * 32 + g * 8]);
        oacc[nt] = MFMA_F16(pa, vb, oacc[nt]);
      }
    }
    #pragma unroll
    for (int nt = 0; nt < 2; ++nt)
      #pragma unroll
      for (int j = 0; j < 4; ++j)
        ao[wid * 16 + g * 4 + j][h * kHD + nt * 16 + l15] = (f16)oacc[nt][j];
    __syncthreads();  // protect q_s/k_s/vT overwrite next head
  }

  __syncthreads();

  // ---- proj: out_win(64x384) = ao(64x384) @ W_proj(384x384) ----
  // wave (wm,wn): rows 32*wm..+32, cols 192*wn..+192, 3 passes of 64 cols
  const size_t outbase = (size_t)b * kNTok * kC;
  #pragma unroll 1
  for (int pass = 0; pass < 3; ++pass) {
    f32x4 pacc[2][4];
    #pragma unroll
    for (int mt = 0; mt < 2; ++mt)
      #pragma unroll
      for (int nt = 0; nt < 4; ++nt) pacc[mt][nt] = zero4;
    int ncol0 = wn * 192 + pass * 64;
    #pragma unroll 2
    for (int ks = 0; ks < 12; ++ks) {
      f16x8 af[2];
      #pragma unroll
      for (int mt = 0; mt < 2; ++mt)
        af[mt] = *reinterpret_cast<const f16x8*>(
            &ao[wm * 32 + mt * 16 + l15][ks * 32 + g * 8]);
      f16x8 bf[4];
      #pragma unroll
      for (int nt = 0; nt < 4; ++nt) {
        int n = ncol0 + nt * 16 + l15;
        bf[nt] = *reinterpret_cast<const f16x8*>(
            &wp_t[(size_t)n * kC + ks * 32 + g * 8]);
      }
      #pragma unroll
      for (int mt = 0; mt < 2; ++mt)
        #pragma unroll
        for (int nt = 0; nt < 4; ++nt)
          pacc[mt][nt] = MFMA_F16(af[mt], bf[nt], pacc[mt][nt]);
    }
    // write out (un-window rows), fp32
    #pragma unroll
    for (int mt = 0; mt < 2; ++mt) {
      #pragma unroll
      for (int j = 0; j < 4; ++j) {
        int r = wm * 32 + mt * 16 + g * 4 + j;
        int n = (wh * 8 + (r >> 3)) * 64 + ww * 8 + (r & 7);
        float* orow = out + outbase + (size_t)n * kC + ncol0;
        #pragma unroll
        for (int nt = 0; nt < 4; ++nt) orow[nt * 16 + l15] = pacc[mt][nt][j];
      }
    }
  }
}

extern "C" void kernel_launch(void* const* d_in, const int* in_sizes, int n_in,
                              void* d_out, int out_size, void* d_ws,
                              size_t ws_size, hipStream_t stream) {
  const float* x = (const float*)d_in[0];
  const float* Wqkv = (const float*)d_in[1];
  const float* bqkv = (const float*)d_in[2];
  const float* Wproj = (const float*)d_in[3];
  float* out = (float*)d_out;

  f16* wt_qkv = (f16*)d_ws;                                   // 884736 B
  f16* wp_t = (f16*)((char*)d_ws + (size_t)kWtQkvElems * 2);  // 294912 B

  int prep_threads = kWtQkvElems + kWpElems;  // 589824
  hipLaunchKernelGGL(prep_weights, dim3((prep_threads + 255) / 256), dim3(256),
                     0, stream, Wqkv, Wproj, wt_qkv, wp_t);
  hipLaunchKernelGGL(win_attn_fused, dim3(16 * 64), dim3(256), 0, stream, x,
                     bqkv, wt_qkv, wp_t, out);
}

// Round 2
// 396.787 us; speedup vs baseline: 1.0649x; 1.0649x over previous
//
#include <hip/hip_runtime.h>
#include <hip/hip_bf16.h>

// WindowAttention fused kernel for MI355X (gfx950) — round 2.
// Changes vs round 1 (which was 1 wave/SIMD, latency-bound: MfmaUtil 7.5%,
// Occupancy 11.9%):
//  - 512 threads (8 waves) per block -> 2 waves/SIMD at 1 block/CU.
//  - 2 heads per attention iteration (wave groups split by head) -> half the
//    barriers; QKV computes a 64x192 slab (2 heads x q|k|v).
//  - Explicit register ring-buffer pipelines for the L2-resident weight
//    fragment streams: QKV depth-3 (ring 4), proj depth-2 (ring 3), A-frags
//    double-buffered. Fully unrolled -> static indexing (no scratch).
//  - p_s (per-wave P tile) write->read barrier removed (wave-private).

typedef _Float16 f16;
typedef f16 f16x8 __attribute__((ext_vector_type(8)));
typedef f16 f16x4 __attribute__((ext_vector_type(4)));
typedef float f32x4 __attribute__((ext_vector_type(4)));

#define MFMA_F16(a, b, c) __builtin_amdgcn_mfma_f32_16x16x32_f16((a), (b), (c), 0, 0, 0)

namespace {
constexpr int kC = 384;
constexpr int kNTok = 4096;
constexpr float kScale = 0.17677669529663687f;  // 1/sqrt(32)
constexpr int kWtQkvElems = 3 * kC * kC;        // 442368
constexpr int kWpElems = kC * kC;               // 147456
}

// ---- weight prep: transpose + f32->f16 ----
__global__ void prep_weights(const float* __restrict__ Wqkv,
                             const float* __restrict__ Wproj,
                             f16* __restrict__ wt_qkv,   // [1152][384]
                             f16* __restrict__ wp_t) {   // [384][384]
  int i = blockIdx.x * 256 + threadIdx.x;
  if (i < kWtQkvElems) {
    int n = i % (3 * kC);
    int k = i / (3 * kC);
    wt_qkv[(size_t)n * kC + k] = (f16)Wqkv[(size_t)k * (3 * kC) + n];
  } else {
    int j = i - kWtQkvElems;
    if (j < kWpElems) {
      int n = j % kC;
      int k = j / kC;
      wp_t[(size_t)n * kC + k] = (f16)Wproj[(size_t)k * kC + n];
    }
  }
}

__global__ __launch_bounds__(512, 2) void win_attn_fused(
    const float* __restrict__ x,
    const float* __restrict__ b_qkv,
    const f16* __restrict__ wt_qkv,
    const f16* __restrict__ wp_t,
    float* __restrict__ out) {
  // LDS: 50176*2 + 10240*2 + 9216 + 18432 = 148480 B (< 160 KiB)
  __shared__ alignas(16) f16 xs[64][392];       // x window (pad +8)
  __shared__ alignas(16) f16 ao[64][392];       // attention output tile
  __shared__ alignas(16) f16 q_s[2][64][40];    // q head tiles [hh][t][d]
  __shared__ alignas(16) f16 k_s[2][64][40];    // k head tiles
  __shared__ alignas(16) f16 vT[2][32][72];     // v transposed [hh][d][t]
  __shared__ alignas(16) f16 p_s[8][16][72];    // per-wave P tile

  const int tid = threadIdx.x;
  const int wid = tid >> 6;      // 0..7
  const int lane = tid & 63;
  const int g = lane >> 4;       // 0..3
  const int l15 = lane & 15;
  const int wm = wid >> 2;       // 0..1  (row half / head-sub)
  const int wn = wid & 3;        // 0..3  (col group / row tile)

  const int blk = blockIdx.x;
  const int b = blk >> 6;
  const int win = blk & 63;
  const int wh = win >> 3;
  const int ww = win & 7;

  const f32x4 zero4 = {0.f, 0.f, 0.f, 0.f};

  // ---- stage x window: 64 rows x 384 cols, f32 -> f16 ----
  {
    const float* xb = x + (size_t)b * kNTok * kC;
    #pragma unroll
    for (int it = 0; it < 12; ++it) {
      int idx = tid + it * 512;          // 64 rows x 96 float4
      int r = idx / 96;
      int c4 = idx - r * 96;
      int n = (wh * 8 + (r >> 3)) * 64 + ww * 8 + (r & 7);
      float4 v = *reinterpret_cast<const float4*>(xb + (size_t)n * kC + c4 * 4);
      f16x4 hv = {(f16)v.x, (f16)v.y, (f16)v.z, (f16)v.w};
      *reinterpret_cast<f16x4*>(&xs[r][c4 * 4]) = hv;
    }
  }
  __syncthreads();

  for (int hp = 0; hp < 6; ++hp) {    // head pair: heads 2hp, 2hp+1
    // ---- QKV slab GEMM: (64 x 192) = xs(64x384) @ Wslab(384x192) ----
    // wave (wm,wn): rows wm*32 (2 m-tiles), cols wn*48 (3 n-tiles)
    // col mapping: base = wn*48+nt*16; hh=base/96; sec=(base%96)/32; db=base%32
    f32x4 acc[2][3];
    #pragma unroll
    for (int mt = 0; mt < 2; ++mt)
      #pragma unroll
      for (int nt = 0; nt < 3; ++nt) acc[mt][nt] = zero4;

    const f16* bptr[3];
    int secv[3], dbv[3], hhv[3];
    #pragma unroll
    for (int nt = 0; nt < 3; ++nt) {
      int base = wn * 48 + nt * 16;
      int hh = base / 96;
      int cc = base - hh * 96;
      int sec = cc >> 5;
      int db = cc & 31;
      hhv[nt] = hh; secv[nt] = sec; dbv[nt] = db;
      int grow = sec * kC + (2 * hp + hh) * 32 + db + l15;
      bptr[nt] = wt_qkv + (size_t)grow * kC + g * 8;
    }

    f16x8 bf[4][3];   // ring-4: prefetch depth 3 on L2 weight stream
    f16x8 af[2][2];   // double-buffered LDS A frags
    #pragma unroll
    for (int p = 0; p < 3; ++p)
      #pragma unroll
      for (int nt = 0; nt < 3; ++nt)
        bf[p][nt] = *reinterpret_cast<const f16x8*>(bptr[nt] + p * 32);
    #pragma unroll
    for (int mt = 0; mt < 2; ++mt)
      af[0][mt] = *reinterpret_cast<const f16x8*>(
          &xs[wm * 32 + mt * 16 + l15][g * 8]);

    #pragma unroll
    for (int ks = 0; ks < 12; ++ks) {
      const int cur = ks & 3;
      const int ca = ks & 1;
      if (ks < 9) {
        const int nx = (ks + 3) & 3;
        #pragma unroll
        for (int nt = 0; nt < 3; ++nt)
          bf[nx][nt] =
              *reinterpret_cast<const f16x8*>(bptr[nt] + (ks + 3) * 32);
      }
      if (ks < 11) {
        #pragma unroll
        for (int mt = 0; mt < 2; ++mt)
          af[ca ^ 1][mt] = *reinterpret_cast<const f16x8*>(
              &xs[wm * 32 + mt * 16 + l15][(ks + 1) * 32 + g * 8]);
      }
      #pragma unroll
      for (int mt = 0; mt < 2; ++mt)
        #pragma unroll
        for (int nt = 0; nt < 3; ++nt)
          acc[mt][nt] = MFMA_F16(af[ca][mt], bf[cur][nt], acc[mt][nt]);
    }

    // scatter q/k/v tiles to LDS (+bias); sec/hh wave-uniform per nt
    #pragma unroll
    for (int nt = 0; nt < 3; ++nt) {
      int hh = hhv[nt], sec = secv[nt];
      int col = dbv[nt] + l15;
      float bias = b_qkv[sec * kC + (2 * hp + hh) * 32 + col];
      #pragma unroll
      for (int mt = 0; mt < 2; ++mt) {
        #pragma unroll
        for (int j = 0; j < 4; ++j) {
          int r = wm * 32 + mt * 16 + g * 4 + j;
          f16 hv = (f16)(acc[mt][nt][j] + bias);
          if (sec == 0) q_s[hh][r][col] = hv;
          else if (sec == 1) k_s[hh][r][col] = hv;
          else vT[hh][col][r] = hv;
        }
      }
    }
    __syncthreads();

    // ---- attention for head h = 2hp + wm; wave rows wn*16..+16 ----
    f32x4 sacc[4];
    #pragma unroll
    for (int nt = 0; nt < 4; ++nt) sacc[nt] = zero4;
    f16x8 qa = *reinterpret_cast<const f16x8*>(&q_s[wm][wn * 16 + l15][g * 8]);
    #pragma unroll
    for (int nt = 0; nt < 4; ++nt) {
      f16x8 kb = *reinterpret_cast<const f16x8*>(&k_s[wm][nt * 16 + l15][g * 8]);
      sacc[nt] = MFMA_F16(qa, kb, sacc[nt]);
    }

    // softmax per row; row r=4g+j lives in the 16 lanes of group g
    float pv[4][4];
    #pragma unroll
    for (int j = 0; j < 4; ++j) {
      float m = -1e30f;
      #pragma unroll
      for (int nt = 0; nt < 4; ++nt) {
        pv[nt][j] = sacc[nt][j] * kScale;
        m = fmaxf(m, pv[nt][j]);
      }
      m = fmaxf(m, __shfl_xor(m, 1));
      m = fmaxf(m, __shfl_xor(m, 2));
      m = fmaxf(m, __shfl_xor(m, 4));
      m = fmaxf(m, __shfl_xor(m, 8));
      float s = 0.f;
      #pragma unroll
      for (int nt = 0; nt < 4; ++nt) {
        pv[nt][j] = __expf(pv[nt][j] - m);
        s += pv[nt][j];
      }
      s += __shfl_xor(s, 1);
      s += __shfl_xor(s, 2);
      s += __shfl_xor(s, 4);
      s += __shfl_xor(s, 8);
      float inv = 1.0f / s;
      #pragma unroll
      for (int nt = 0; nt < 4; ++nt)
        p_s[wid][g * 4 + j][nt * 16 + l15] = (f16)(pv[nt][j] * inv);
    }
    // no barrier: p_s[wid] is wave-private; in-wave LDS order via lgkmcnt

    // ---- O = P @ V : wave rows 16, cols 32, K=64 ----
    f32x4 oacc[2];
    oacc[0] = zero4;
    oacc[1] = zero4;
    #pragma unroll
    for (int ks = 0; ks < 2; ++ks) {
      f16x8 pa = *reinterpret_cast<const f16x8*>(
          &p_s[wid][l15][ks * 32 + g * 8]);
      #pragma unroll
      for (int nt = 0; nt < 2; ++nt) {
        f16x8 vb = *reinterpret_cast<const f16x8*>(
            &vT[wm][nt * 16 + l15][ks * 32 + g * 8]);
        oacc[nt] = MFMA_F16(pa, vb, oacc[nt]);
      }
    }
    #pragma unroll
    for (int nt = 0; nt < 2; ++nt)
      #pragma unroll
      for (int j = 0; j < 4; ++j)
        ao[wn * 16 + g * 4 + j][(2 * hp + wm) * 32 + nt * 16 + l15] =
            (f16)oacc[nt][j];
    __syncthreads();  // protect q_s/k_s/vT overwrite next head pair
  }

  // ---- proj: out_win(64x384) = ao(64x384) @ W_proj(384x384), one pass ----
  // wave (wm,wn): rows wm*32 (2 m-tiles), cols wn*96 (6 n-tiles)
  f32x4 pacc[2][6];
  #pragma unroll
  for (int mt = 0; mt < 2; ++mt)
    #pragma unroll
    for (int nt = 0; nt < 6; ++nt) pacc[mt][nt] = zero4;

  const f16* pptr[6];
  #pragma unroll
  for (int nt = 0; nt < 6; ++nt) {
    int n = wn * 96 + nt * 16 + l15;
    pptr[nt] = wp_t + (size_t)n * kC + g * 8;
  }
  f16x8 pbf[3][6];   // ring-3: prefetch depth 2
  f16x8 paf[2][2];
  #pragma unroll
  for (int p = 0; p < 2; ++p)
    #pragma unroll
    for (int nt = 0; nt < 6; ++nt)
      pbf[p][nt] = *reinterpret_cast<const f16x8*>(pptr[nt] + p * 32);
  #pragma unroll
  for (int mt = 0; mt < 2; ++mt)
    paf[0][mt] = *reinterpret_cast<const f16x8*>(
        &ao[wm * 32 + mt * 16 + l15][g * 8]);

  #pragma unroll
  for (int ks = 0; ks < 12; ++ks) {
    const int cur = ks % 3;
    const int ca = ks & 1;
    if (ks < 10) {
      const int nx = (ks + 2) % 3;
      #pragma unroll
      for (int nt = 0; nt < 6; ++nt)
        pbf[nx][nt] = *reinterpret_cast<const f16x8*>(pptr[nt] + (ks + 2) * 32);
    }
    if (ks < 11) {
      #pragma unroll
      for (int mt = 0; mt < 2; ++mt)
        paf[ca ^ 1][mt] = *reinterpret_cast<const f16x8*>(
            &ao[wm * 32 + mt * 16 + l15][(ks + 1) * 32 + g * 8]);
    }
    #pragma unroll
    for (int mt = 0; mt < 2; ++mt)
      #pragma unroll
      for (int nt = 0; nt < 6; ++nt)
        pacc[mt][nt] = MFMA_F16(paf[ca][mt], pbf[cur][nt], pacc[mt][nt]);
  }

  // write out (un-window rows), fp32
  const size_t outbase = (size_t)b * kNTok * kC;
  #pragma unroll
  for (int mt = 0; mt < 2; ++mt) {
    #pragma unroll
    for (int j = 0; j < 4; ++j) {
      int r = wm * 32 + mt * 16 + g * 4 + j;
      int n = (wh * 8 + (r >> 3)) * 64 + ww * 8 + (r & 7);
      float* orow = out + outbase + (size_t)n * kC + wn * 96;
      #pragma unroll
      for (int nt = 0; nt < 6; ++nt) orow[nt * 16 + l15] = pacc[mt][nt][j];
    }
  }
}

extern "C" void kernel_launch(void* const* d_in, const int* in_sizes, int n_in,
                              void* d_out, int out_size, void* d_ws,
                              size_t ws_size, hipStream_t stream) {
  const float* x = (const float*)d_in[0];
  const float* Wqkv = (const float*)d_in[1];
  const float* bqkv = (const float*)d_in[2];
  const float* Wproj = (const float*)d_in[3];
  float* out = (float*)d_out;

  f16* wt_qkv = (f16*)d_ws;                                   // 884736 B
  f16* wp_t = (f16*)((char*)d_ws + (size_t)kWtQkvElems * 2);  // 294912 B

  int prep_threads = kWtQkvElems + kWpElems;
  hipLaunchKernelGGL(prep_weights, dim3((prep_threads + 255) / 256), dim3(256),
                     0, stream, Wqkv, Wproj, wt_qkv, wp_t);
  hipLaunchKernelGGL(win_attn_fused, dim3(16 * 64), dim3(512), 0, stream, x,
                     bqkv, wt_qkv, wp_t, out);
}

// Round 3
// 240.029 us; speedup vs baseline: 1.7604x; 1.6531x over previous
//
#include <hip/hip_runtime.h>
#include <hip/hip_bf16.h>

// WindowAttention fused kernel for MI355X (gfx950) — round 3.
// Diagnosis from R1/R2: per-block time invariant under 2x occupancy and 0.5x
// per-wave loads -> bottleneck = address-divergence throughput of the weight
// B-fragment loads (each wave-load was a 16-cache-line gather, rows stride
// 768 B). Fix: pre-pack W_qkv / W_proj in exact MFMA fragment order
// pack[(tile, ks, lane, j)], lane = g*16+l15 -> every B-load is one fully
// coalesced 1 KB contiguous wave-load from L2.

typedef _Float16 f16;
typedef f16 f16x8 __attribute__((ext_vector_type(8)));
typedef f16 f16x4 __attribute__((ext_vector_type(4)));
typedef float f32x4 __attribute__((ext_vector_type(4)));

#define MFMA_F16(a, b, c) __builtin_amdgcn_mfma_f32_16x16x32_f16((a), (b), (c), 0, 0, 0)

namespace {
constexpr int kC = 384;
constexpr int kNTok = 4096;
constexpr float kScale = 0.17677669529663687f;  // 1/sqrt(32)
constexpr int kQkvPackChunks = 6 * 12 * 12 * 64;  // 55296 x 16B
constexpr int kProjPackChunks = 24 * 12 * 64;     // 18432 x 16B
}

// ---- weight prep: pack into fragment order ----
// wq_pack frag(hp, t, ks, lane, j):  t in [0,12) tiles the 192-col head-pair
//   slab; element = W_qkv[k = ks*32 + (lane>>4)*8 + j][n3], with
//   n3 = sec*384 + (2hp+hh)*32 + dbhi + (lane&15), (hh,sec,dbhi) from t.
// wp_pack frag(t, ks, lane, j): element = W_proj[ks*32+(lane>>4)*8+j][t*16+(lane&15)]
__global__ void prep_weights(const float* __restrict__ Wqkv,
                             const float* __restrict__ Wproj,
                             f16* __restrict__ wq_pack,
                             f16* __restrict__ wp_pack) {
  int i = blockIdx.x * 256 + threadIdx.x;  // one thread per 16-B dest chunk
  if (i < kQkvPackChunks) {
    int lane = i & 63;
    int chunk = i >> 6;
    int ks = chunk % 12;
    int t = (chunk / 12) % 12;
    int hp = chunk / 144;
    int l15 = lane & 15, g = lane >> 4;
    int base = t * 16;
    int hh = base / 96;
    int cc = base - hh * 96;
    int sec = cc >> 5;
    int dbhi = cc & 31;  // 0 or 16
    int n3 = sec * kC + (2 * hp + hh) * 32 + dbhi + l15;
    int k0 = ks * 32 + g * 8;
    f16x8 v;
    #pragma unroll
    for (int j = 0; j < 8; ++j)
      v[j] = (f16)Wqkv[(size_t)(k0 + j) * (3 * kC) + n3];
    *reinterpret_cast<f16x8*>(wq_pack + (size_t)i * 8) = v;
  } else if (i < kQkvPackChunks + kProjPackChunks) {
    int p = i - kQkvPackChunks;
    int lane = p & 63;
    int chunk = p >> 6;
    int ks = chunk % 12;
    int t = chunk / 12;
    int l15 = lane & 15, g = lane >> 4;
    int n = t * 16 + l15;
    int k0 = ks * 32 + g * 8;
    f16x8 v;
    #pragma unroll
    for (int j = 0; j < 8; ++j)
      v[j] = (f16)Wproj[(size_t)(k0 + j) * kC + n];
    *reinterpret_cast<f16x8*>(wp_pack + (size_t)p * 8) = v;
  }
}

__global__ __launch_bounds__(512, 2) void win_attn_fused(
    const float* __restrict__ x,
    const float* __restrict__ b_qkv,
    const f16* __restrict__ wq_pack,
    const f16* __restrict__ wp_pack,
    float* __restrict__ out) {
  // LDS: 50176*2 + 10240*2 + 9216 + 18432 = 148480 B (< 160 KiB)
  __shared__ alignas(16) f16 xs[64][392];       // x window (pad +8)
  __shared__ alignas(16) f16 ao[64][392];       // attention output tile
  __shared__ alignas(16) f16 q_s[2][64][40];    // q head tiles [hh][t][d]
  __shared__ alignas(16) f16 k_s[2][64][40];    // k head tiles
  __shared__ alignas(16) f16 vT[2][32][72];     // v transposed [hh][d][t]
  __shared__ alignas(16) f16 p_s[8][16][72];    // per-wave P tile

  const int tid = threadIdx.x;
  const int wid = tid >> 6;      // 0..7
  const int lane = tid & 63;
  const int g = lane >> 4;       // 0..3
  const int l15 = lane & 15;
  const int wm = wid >> 2;       // 0..1  (row half / head-sub)
  const int wn = wid & 3;        // 0..3  (col group / row tile)

  const int blk = blockIdx.x;
  const int b = blk >> 6;
  const int win = blk & 63;
  const int wh = win >> 3;
  const int ww = win & 7;

  const f32x4 zero4 = {0.f, 0.f, 0.f, 0.f};

  // ---- stage x window: 64 rows x 384 cols, f32 -> f16 ----
  {
    const float* xb = x + (size_t)b * kNTok * kC;
    #pragma unroll
    for (int it = 0; it < 12; ++it) {
      int idx = tid + it * 512;          // 64 rows x 96 float4
      int r = idx / 96;
      int c4 = idx - r * 96;
      int n = (wh * 8 + (r >> 3)) * 64 + ww * 8 + (r & 7);
      float4 v = *reinterpret_cast<const float4*>(xb + (size_t)n * kC + c4 * 4);
      f16x4 hv = {(f16)v.x, (f16)v.y, (f16)v.z, (f16)v.w};
      *reinterpret_cast<f16x4*>(&xs[r][c4 * 4]) = hv;
    }
  }
  __syncthreads();

  for (int hp = 0; hp < 6; ++hp) {    // head pair: heads 2hp, 2hp+1
    // ---- QKV slab GEMM: (64 x 192) = xs(64x384) @ Wslab(384x192) ----
    // wave (wm,wn): rows wm*32 (2 m-tiles), col tiles t = wn*3+nt (3 n-tiles)
    f32x4 acc[2][3];
    #pragma unroll
    for (int mt = 0; mt < 2; ++mt)
      #pragma unroll
      for (int nt = 0; nt < 3; ++nt) acc[mt][nt] = zero4;

    const f16* bptr[3];
    int secv[3], dbv[3], hhv[3];
    #pragma unroll
    for (int nt = 0; nt < 3; ++nt) {
      int t = wn * 3 + nt;
      int base = t * 16;
      int hh = base / 96;
      int cc = base - hh * 96;
      hhv[nt] = hh;
      secv[nt] = cc >> 5;
      dbv[nt] = cc & 31;
      // frag(hp,t,ks,lane): ks stride = 64*8 = 512 halves (1 KB)
      bptr[nt] = wq_pack + ((size_t)((hp * 12 + t) * 12) * 64 + lane) * 8;
    }

    f16x8 bf[4][3];   // ring-4: prefetch depth 3 on coalesced L2 stream
    f16x8 af[2][2];   // double-buffered LDS A frags
    #pragma unroll
    for (int p = 0; p < 3; ++p)
      #pragma unroll
      for (int nt = 0; nt < 3; ++nt)
        bf[p][nt] = *reinterpret_cast<const f16x8*>(bptr[nt] + p * 512);
    #pragma unroll
    for (int mt = 0; mt < 2; ++mt)
      af[0][mt] = *reinterpret_cast<const f16x8*>(
          &xs[wm * 32 + mt * 16 + l15][g * 8]);

    #pragma unroll
    for (int ks = 0; ks < 12; ++ks) {
      const int cur = ks & 3;
      const int ca = ks & 1;
      if (ks < 9) {
        const int nx = (ks + 3) & 3;
        #pragma unroll
        for (int nt = 0; nt < 3; ++nt)
          bf[nx][nt] =
              *reinterpret_cast<const f16x8*>(bptr[nt] + (ks + 3) * 512);
      }
      if (ks < 11) {
        #pragma unroll
        for (int mt = 0; mt < 2; ++mt)
          af[ca ^ 1][mt] = *reinterpret_cast<const f16x8*>(
              &xs[wm * 32 + mt * 16 + l15][(ks + 1) * 32 + g * 8]);
      }
      #pragma unroll
      for (int mt = 0; mt < 2; ++mt)
        #pragma unroll
        for (int nt = 0; nt < 3; ++nt)
          acc[mt][nt] = MFMA_F16(af[ca][mt], bf[cur][nt], acc[mt][nt]);
    }

    // scatter q/k/v tiles to LDS (+bias); sec/hh wave-uniform per nt
    #pragma unroll
    for (int nt = 0; nt < 3; ++nt) {
      int hh = hhv[nt], sec = secv[nt];
      int col = dbv[nt] + l15;
      float bias = b_qkv[sec * kC + (2 * hp + hh) * 32 + col];
      #pragma unroll
      for (int mt = 0; mt < 2; ++mt) {
        #pragma unroll
        for (int j = 0; j < 4; ++j) {
          int r = wm * 32 + mt * 16 + g * 4 + j;
          f16 hv = (f16)(acc[mt][nt][j] + bias);
          if (sec == 0) q_s[hh][r][col] = hv;
          else if (sec == 1) k_s[hh][r][col] = hv;
          else vT[hh][col][r] = hv;
        }
      }
    }
    __syncthreads();

    // ---- attention for head h = 2hp + wm; wave rows wn*16..+16 ----
    f32x4 sacc[4];
    #pragma unroll
    for (int nt = 0; nt < 4; ++nt) sacc[nt] = zero4;
    f16x8 qa = *reinterpret_cast<const f16x8*>(&q_s[wm][wn * 16 + l15][g * 8]);
    #pragma unroll
    for (int nt = 0; nt < 4; ++nt) {
      f16x8 kb = *reinterpret_cast<const f16x8*>(&k_s[wm][nt * 16 + l15][g * 8]);
      sacc[nt] = MFMA_F16(qa, kb, sacc[nt]);
    }

    // softmax per row; row r=4g+j lives in the 16 lanes of group g
    float pv[4][4];
    #pragma unroll
    for (int j = 0; j < 4; ++j) {
      float m = -1e30f;
      #pragma unroll
      for (int nt = 0; nt < 4; ++nt) {
        pv[nt][j] = sacc[nt][j] * kScale;
        m = fmaxf(m, pv[nt][j]);
      }
      m = fmaxf(m, __shfl_xor(m, 1));
      m = fmaxf(m, __shfl_xor(m, 2));
      m = fmaxf(m, __shfl_xor(m, 4));
      m = fmaxf(m, __shfl_xor(m, 8));
      float s = 0.f;
      #pragma unroll
      for (int nt = 0; nt < 4; ++nt) {
        pv[nt][j] = __expf(pv[nt][j] - m);
        s += pv[nt][j];
      }
      s += __shfl_xor(s, 1);
      s += __shfl_xor(s, 2);
      s += __shfl_xor(s, 4);
      s += __shfl_xor(s, 8);
      float inv = 1.0f / s;
      #pragma unroll
      for (int nt = 0; nt < 4; ++nt)
        p_s[wid][g * 4 + j][nt * 16 + l15] = (f16)(pv[nt][j] * inv);
    }
    // no barrier: p_s[wid] is wave-private; in-wave LDS order via lgkmcnt

    // ---- O = P @ V : wave rows 16, cols 32, K=64 ----
    f32x4 oacc[2];
    oacc[0] = zero4;
    oacc[1] = zero4;
    #pragma unroll
    for (int ks = 0; ks < 2; ++ks) {
      f16x8 pa = *reinterpret_cast<const f16x8*>(
          &p_s[wid][l15][ks * 32 + g * 8]);
      #pragma unroll
      for (int nt = 0; nt < 2; ++nt) {
        f16x8 vb = *reinterpret_cast<const f16x8*>(
            &vT[wm][nt * 16 + l15][ks * 32 + g * 8]);
        oacc[nt] = MFMA_F16(pa, vb, oacc[nt]);
      }
    }
    #pragma unroll
    for (int nt = 0; nt < 2; ++nt)
      #pragma unroll
      for (int j = 0; j < 4; ++j)
        ao[wn * 16 + g * 4 + j][(2 * hp + wm) * 32 + nt * 16 + l15] =
            (f16)oacc[nt][j];
    __syncthreads();  // protect q_s/k_s/vT overwrite next head pair
  }

  // ---- proj: out_win(64x384) = ao(64x384) @ W_proj(384x384), one pass ----
  // wave (wm,wn): rows wm*32 (2 m-tiles), col tiles t = wn*6+nt (6 n-tiles)
  f32x4 pacc[2][6];
  #pragma unroll
  for (int mt = 0; mt < 2; ++mt)
    #pragma unroll
    for (int nt = 0; nt < 6; ++nt) pacc[mt][nt] = zero4;

  const f16* pptr[6];
  #pragma unroll
  for (int nt = 0; nt < 6; ++nt) {
    int t = wn * 6 + nt;
    pptr[nt] = wp_pack + ((size_t)(t * 12) * 64 + lane) * 8;
  }
  f16x8 pbf[3][6];   // ring-3: prefetch depth 2
  f16x8 paf[2][2];
  #pragma unroll
  for (int p = 0; p < 2; ++p)
    #pragma unroll
    for (int nt = 0; nt < 6; ++nt)
      pbf[p][nt] = *reinterpret_cast<const f16x8*>(pptr[nt] + p * 512);
  #pragma unroll
  for (int mt = 0; mt < 2; ++mt)
    paf[0][mt] = *reinterpret_cast<const f16x8*>(
        &ao[wm * 32 + mt * 16 + l15][g * 8]);

  #pragma unroll
  for (int ks = 0; ks < 12; ++ks) {
    const int cur = ks % 3;
    const int ca = ks & 1;
    if (ks < 10) {
      const int nx = (ks + 2) % 3;
      #pragma unroll
      for (int nt = 0; nt < 6; ++nt)
        pbf[nx][nt] =
            *reinterpret_cast<const f16x8*>(pptr[nt] + (ks + 2) * 512);
    }
    if (ks < 11) {
      #pragma unroll
      for (int mt = 0; mt < 2; ++mt)
        paf[ca ^ 1][mt] = *reinterpret_cast<const f16x8*>(
            &ao[wm * 32 + mt * 16 + l15][(ks + 1) * 32 + g * 8]);
    }
    #pragma unroll
    for (int mt = 0; mt < 2; ++mt)
      #pragma unroll
      for (int nt = 0; nt < 6; ++nt)
        pacc[mt][nt] = MFMA_F16(paf[ca][mt], pbf[cur][nt], pacc[mt][nt]);
  }

  // write out (un-window rows), fp32
  const size_t outbase = (size_t)b * kNTok * kC;
  #pragma unroll
  for (int mt = 0; mt < 2; ++mt) {
    #pragma unroll
    for (int j = 0; j < 4; ++j) {
      int r = wm * 32 + mt * 16 + g * 4 + j;
      int n = (wh * 8 + (r >> 3)) * 64 + ww * 8 + (r & 7);
      float* orow = out + outbase + (size_t)n * kC + wn * 96;
      #pragma unroll
      for (int nt = 0; nt < 6; ++nt) orow[nt * 16 + l15] = pacc[mt][nt][j];
    }
  }
}

extern "C" void kernel_launch(void* const* d_in, const int* in_sizes, int n_in,
                              void* d_out, int out_size, void* d_ws,
                              size_t ws_size, hipStream_t stream) {
  const float* x = (const float*)d_in[0];
  const float* Wqkv = (const float*)d_in[1];
  const float* bqkv = (const float*)d_in[2];
  const float* Wproj = (const float*)d_in[3];
  float* out = (float*)d_out;

  f16* wq_pack = (f16*)d_ws;                                      // 884736 B
  f16* wp_pack = (f16*)((char*)d_ws + (size_t)kQkvPackChunks * 16);  // 294912 B

  int prep_threads = kQkvPackChunks + kProjPackChunks;  // 73728
  hipLaunchKernelGGL(prep_weights, dim3((prep_threads + 255) / 256), dim3(256),
                     0, stream, Wqkv, Wproj, wq_pack, wp_pack);
  hipLaunchKernelGGL(win_attn_fused, dim3(16 * 64), dim3(512), 0, stream, x,
                     bqkv, wq_pack, wp_pack, out);
}

// Round 4
// 236.686 us; speedup vs baseline: 1.7853x; 1.0141x over previous
//
#include <hip/hip_runtime.h>
#include <hip/hip_bf16.h>

// WindowAttention for MI355X (gfx950) — round 4: split design.
// R3 diagnosis: fused kernel's 64-row M-tile gives ~63 FLOP per L2 byte on the
// weight streams -> QKV/proj phases are L2-BW/latency bound (MfmaUtil 12.9%).
// Fix:
//  K1 qkv_gemm: real GEMM M=65536 N=1152 K=384, 128x128 tile, A (x f32)
//     reg-staged->f16 LDS dbuf, B from fragment-packed f16 global (L2-res),
//     XCD-swizzled grid (n-major within XCD -> A-panel L2 reuse). Writes qkv
//     f16 to ws packed per (b,win,head)[q|k|v][64][32].
//  K2 attn_proj: per-window block (512 thr, 76 KB LDS -> 2 blocks/CU):
//     q/k fragments straight from packed global, v transposed via small LDS
//     tile, softmax in-register, proj GEMM from LDS ao tile.
// Fallback to the round-3 fused kernel if ws_size < ~146 MB.

typedef _Float16 f16;
typedef f16 f16x8 __attribute__((ext_vector_type(8)));
typedef f16 f16x4 __attribute__((ext_vector_type(4)));
typedef float f32x4 __attribute__((ext_vector_type(4)));

#define MFMA_F16(a, b, c) __builtin_amdgcn_mfma_f32_16x16x32_f16((a), (b), (c), 0, 0, 0)

namespace {
constexpr int kC = 384;
constexpr int kNTok = 4096;
constexpr float kScale = 0.17677669529663687f;  // 1/sqrt(32)
// split-path ws layout
constexpr int kQkvTiles = 72;                       // 1152/16
constexpr int kWqPackChunks = kQkvTiles * 12 * 64;  // 55296 x 16B
constexpr int kWpPackChunks = 24 * 12 * 64;         // 18432 x 16B
constexpr size_t kWqPackBytes = (size_t)kWqPackChunks * 16;  // 884736
constexpr size_t kWpPackBytes = (size_t)kWpPackChunks * 16;  // 294912
constexpr size_t kQkvWsBytes = (size_t)65536 * 1152 * 2;     // 150994944
constexpr size_t kWsNeed = kWqPackBytes + kWpPackBytes + kQkvWsBytes;
// fallback (round-3) ws layout
constexpr int kQkvPackChunksFb = 6 * 12 * 12 * 64;  // 55296
}

// ===================== split path =====================

// pack Wqkv/Wproj f16 in B-fragment order: chunk=(t,ks), lane=g*16+l15,
// elem j = W[ks*32+g*8+j][t*16+l15]
__global__ void prep_weights_split(const float* __restrict__ Wqkv,
                                   const float* __restrict__ Wproj,
                                   f16* __restrict__ wq_pack,
                                   f16* __restrict__ wp_pack) {
  int i = blockIdx.x * 256 + threadIdx.x;
  if (i < kWqPackChunks) {
    int lane = i & 63;
    int chunk = i >> 6;
    int ks = chunk % 12;
    int t = chunk / 12;
    int l15 = lane & 15, g = lane >> 4;
    int n3 = t * 16 + l15;
    int k0 = ks * 32 + g * 8;
    f16x8 v;
    #pragma unroll
    for (int j = 0; j < 8; ++j)
      v[j] = (f16)Wqkv[(size_t)(k0 + j) * (3 * kC) + n3];
    *reinterpret_cast<f16x8*>(wq_pack + (size_t)i * 8) = v;
  } else if (i < kWqPackChunks + kWpPackChunks) {
    int p = i - kWqPackChunks;
    int lane = p & 63;
    int chunk = p >> 6;
    int ks = chunk % 12;
    int t = chunk / 12;
    int l15 = lane & 15, g = lane >> 4;
    int n = t * 16 + l15;
    int k0 = ks * 32 + g * 8;
    f16x8 v;
    #pragma unroll
    for (int j = 0; j < 8; ++j)
      v[j] = (f16)Wproj[(size_t)(k0 + j) * kC + n];
    *reinterpret_cast<f16x8*>(wp_pack + (size_t)p * 8) = v;
  }
}

// K1: qkv = x @ Wqkv + b, f16 output packed [b][win][h][q|k|v][tok][d]
__global__ __launch_bounds__(256, 3) void qkv_gemm(
    const float* __restrict__ x, const float* __restrict__ b_qkv,
    const f16* __restrict__ wq_pack, f16* __restrict__ qkv_ws) {
  __shared__ alignas(16) f16 As[2][128][40];  // 20480 B, pad 40 (2-way banks)

  const int tid = threadIdx.x;
  const int wid = tid >> 6;  // 0..3
  const int lane = tid & 63;
  const int g = lane >> 4;
  const int l15 = lane & 15;
  const int wm = wid >> 1;
  const int wn = wid & 1;

  // XCD swizzle: 4608 = 8*576; same-XCD gets contiguous wg range; wg n-major
  int bid = blockIdx.x;
  int wg = (bid & 7) * 576 + (bid >> 3);
  int m_grp = wg / 9;
  int n_grp = wg - m_grp * 9;
  const size_t m0 = (size_t)m_grp * 128;

  // staging: thread -> (row, 16-float half-row)
  const int srow = tid >> 1;
  const int scol = (tid & 1) * 16;
  const float* xrow = x + (m0 + srow) * kC + scol;

  const f16* bptr[4];
  #pragma unroll
  for (int nt = 0; nt < 4; ++nt) {
    int t = n_grp * 8 + wn * 4 + nt;
    bptr[nt] = wq_pack + ((size_t)(t * 12) * 64 + lane) * 8;
  }

  f32x4 acc[4][4];
  #pragma unroll
  for (int mt = 0; mt < 4; ++mt)
    #pragma unroll
    for (int nt = 0; nt < 4; ++nt) acc[mt][nt] = {0.f, 0.f, 0.f, 0.f};

  // prologue: stage ks=0 into buf 0
  {
    float4 v0 = *reinterpret_cast<const float4*>(xrow + 0);
    float4 v1 = *reinterpret_cast<const float4*>(xrow + 4);
    float4 v2 = *reinterpret_cast<const float4*>(xrow + 8);
    float4 v3 = *reinterpret_cast<const float4*>(xrow + 12);
    f16x8 h0 = {(f16)v0.x, (f16)v0.y, (f16)v0.z, (f16)v0.w,
                (f16)v1.x, (f16)v1.y, (f16)v1.z, (f16)v1.w};
    f16x8 h1 = {(f16)v2.x, (f16)v2.y, (f16)v2.z, (f16)v2.w,
                (f16)v3.x, (f16)v3.y, (f16)v3.z, (f16)v3.w};
    *reinterpret_cast<f16x8*>(&As[0][srow][scol]) = h0;
    *reinterpret_cast<f16x8*>(&As[0][srow][scol + 8]) = h1;
  }
  __syncthreads();

  #pragma unroll
  for (int ks = 0; ks < 12; ++ks) {
    const int cur = ks & 1;
    float4 v0, v1, v2, v3;
    if (ks < 11) {  // issue next-chunk x loads early
      const float* p = xrow + (ks + 1) * 32;
      v0 = *reinterpret_cast<const float4*>(p + 0);
      v1 = *reinterpret_cast<const float4*>(p + 4);
      v2 = *reinterpret_cast<const float4*>(p + 8);
      v3 = *reinterpret_cast<const float4*>(p + 12);
    }
    f16x8 af[4];
    #pragma unroll
    for (int mt = 0; mt < 4; ++mt)
      af[mt] = *reinterpret_cast<const f16x8*>(
          &As[cur][wm * 64 + mt * 16 + l15][g * 8]);
    f16x8 bf[4];
    #pragma unroll
    for (int nt = 0; nt < 4; ++nt)
      bf[nt] = *reinterpret_cast<const f16x8*>(bptr[nt] + ks * 512);
    #pragma unroll
    for (int mt = 0; mt < 4; ++mt)
      #pragma unroll
      for (int nt = 0; nt < 4; ++nt)
        acc[mt][nt] = MFMA_F16(af[mt], bf[nt], acc[mt][nt]);
    if (ks < 11) {
      f16x8 h0 = {(f16)v0.x, (f16)v0.y, (f16)v0.z, (f16)v0.w,
                  (f16)v1.x, (f16)v1.y, (f16)v1.z, (f16)v1.w};
      f16x8 h1 = {(f16)v2.x, (f16)v2.y, (f16)v2.z, (f16)v2.w,
                  (f16)v3.x, (f16)v3.y, (f16)v3.z, (f16)v3.w};
      *reinterpret_cast<f16x8*>(&As[cur ^ 1][srow][scol]) = h0;
      *reinterpret_cast<f16x8*>(&As[cur ^ 1][srow][scol + 8]) = h1;
    }
    __syncthreads();
  }

  // epilogue: bias + scatter into packed qkv layout
  #pragma unroll
  for (int nt = 0; nt < 4; ++nt) {
    int gcol = n_grp * 128 + wn * 64 + nt * 16 + l15;
    int sec = gcol / kC;         // tiles are 16-aligned -> no straddle
    int hcol = gcol - sec * kC;
    int h = hcol >> 5;
    int d = hcol & 31;
    float bias = b_qkv[gcol];
    #pragma unroll
    for (int mt = 0; mt < 4; ++mt) {
      #pragma unroll
      for (int j = 0; j < 4; ++j) {
        size_t m = m0 + wm * 64 + mt * 16 + g * 4 + j;
        int b = (int)(m >> 12);
        int n = (int)(m & 4095);
        int rr = n >> 6, cc = n & 63;
        int win = ((rr >> 3) << 3) + (cc >> 3);
        int tok = ((rr & 7) << 3) + (cc & 7);
        size_t addr =
            ((((size_t)(b * 64 + win) * 12 + h) * 3 + sec) * 64 + tok) * 32 + d;
        qkv_ws[addr] = (f16)(acc[mt][nt][j] + bias);
      }
    }
  }
}

// K2: attention + proj per window
__global__ __launch_bounds__(512, 4) void attn_proj(
    const f16* __restrict__ qkv_ws, const f16* __restrict__ wp_pack,
    float* __restrict__ out) {
  // LDS: 50176 + 9216 + 18432 = 77824 B -> 2 blocks/CU
  __shared__ alignas(16) f16 ao[64][392];
  __shared__ alignas(16) f16 vT[2][32][72];
  __shared__ alignas(16) f16 p_s[8][16][72];

  const int tid = threadIdx.x;
  const int wid = tid >> 6;
  const int lane = tid & 63;
  const int g = lane >> 4;
  const int l15 = lane & 15;
  const int wm = wid >> 2;  // head parity
  const int wn = wid & 3;   // row tile

  const int blk = blockIdx.x;
  const int b = blk >> 6;
  const int win = blk & 63;
  const int wh = win >> 3;
  const int ww = win & 7;

  const f32x4 zero4 = {0.f, 0.f, 0.f, 0.f};
  const f16* qkvb = qkv_ws + (size_t)(b * 64 + win) * 12 * 3 * 64 * 32;

  // v-stage mapping: i -> hh=i>>8, tok=(i>>2)&63, d0=(i&3)*8
  const int v_hh = tid >> 8;
  const int v_tok = (tid >> 2) & 63;
  const int v_d0 = (tid & 3) * 8;

  for (int hp = 0; hp < 6; ++hp) {
    // stage v (heads 2hp, 2hp+1) transposed into vT
    {
      int h2 = 2 * hp + v_hh;
      f16x8 v = *reinterpret_cast<const f16x8*>(
          qkvb + ((size_t)(h2 * 3 + 2) * 64 + v_tok) * 32 + v_d0);
      #pragma unroll
      for (int j = 0; j < 8; ++j) vT[v_hh][v_d0 + j][v_tok] = v[j];
    }
    __syncthreads();

    // head for this wave
    const int h = 2 * hp + wm;
    const f16* hb = qkvb + (size_t)h * 3 * 2048;
    f16x8 qa = *reinterpret_cast<const f16x8*>(
        hb + (wn * 16 + l15) * 32 + g * 8);
    f32x4 sacc[4];
    #pragma unroll
    for (int nt = 0; nt < 4; ++nt) sacc[nt] = zero4;
    #pragma unroll
    for (int nt = 0; nt < 4; ++nt) {
      f16x8 kb = *reinterpret_cast<const f16x8*>(
          hb + 2048 + (nt * 16 + l15) * 32 + g * 8);
      sacc[nt] = MFMA_F16(qa, kb, sacc[nt]);
    }

    // softmax per row (row r=g*4+j in the 16 lanes of group g)
    float pv[4][4];
    #pragma unroll
    for (int j = 0; j < 4; ++j) {
      float m = -1e30f;
      #pragma unroll
      for (int nt = 0; nt < 4; ++nt) {
        pv[nt][j] = sacc[nt][j] * kScale;
        m = fmaxf(m, pv[nt][j]);
      }
      m = fmaxf(m, __shfl_xor(m, 1));
      m = fmaxf(m, __shfl_xor(m, 2));
      m = fmaxf(m, __shfl_xor(m, 4));
      m = fmaxf(m, __shfl_xor(m, 8));
      float s = 0.f;
      #pragma unroll
      for (int nt = 0; nt < 4; ++nt) {
        pv[nt][j] = __expf(pv[nt][j] - m);
        s += pv[nt][j];
      }
      s += __shfl_xor(s, 1);
      s += __shfl_xor(s, 2);
      s += __shfl_xor(s, 4);
      s += __shfl_xor(s, 8);
      float inv = 1.0f / s;
      #pragma unroll
      for (int nt = 0; nt < 4; ++nt)
        p_s[wid][g * 4 + j][nt * 16 + l15] = (f16)(pv[nt][j] * inv);
    }
    // no barrier: p_s[wid] wave-private

    // O = P @ V
    f32x4 oacc[2];
    oacc[0] = zero4;
    oacc[1] = zero4;
    #pragma unroll
    for (int ks = 0; ks < 2; ++ks) {
      f16x8 pa =
          *reinterpret_cast<const f16x8*>(&p_s[wid][l15][ks * 32 + g * 8]);
      #pragma unroll
      for (int nt = 0; nt < 2; ++nt) {
        f16x8 vb = *reinterpret_cast<const f16x8*>(
            &vT[wm][nt * 16 + l15][ks * 32 + g * 8]);
        oacc[nt] = MFMA_F16(pa, vb, oacc[nt]);
      }
    }
    #pragma unroll
    for (int nt = 0; nt < 2; ++nt)
      #pragma unroll
      for (int j = 0; j < 4; ++j)
        ao[wn * 16 + g * 4 + j][h * 32 + nt * 16 + l15] = (f16)oacc[nt][j];
    __syncthreads();  // vT consumed before next-hp overwrite; ao published
  }

  // proj: out_win(64x384) = ao @ Wp; wave (wm,wn): rows wm*32, tiles wn*6+nt
  f32x4 pacc[2][6];
  #pragma unroll
  for (int mt = 0; mt < 2; ++mt)
    #pragma unroll
    for (int nt = 0; nt < 6; ++nt) pacc[mt][nt] = zero4;

  const f16* pptr[6];
  #pragma unroll
  for (int nt = 0; nt < 6; ++nt) {
    int t = wn * 6 + nt;
    pptr[nt] = wp_pack + ((size_t)(t * 12) * 64 + lane) * 8;
  }
  f16x8 pbf[2][6];  // ring-2 (VGPR budget: keep block at 2/CU)
  #pragma unroll
  for (int nt = 0; nt < 6; ++nt)
    pbf[0][nt] = *reinterpret_cast<const f16x8*>(pptr[nt]);

  #pragma unroll
  for (int ks = 0; ks < 12; ++ks) {
    const int cur = ks & 1;
    if (ks < 11) {
      #pragma unroll
      for (int nt = 0; nt < 6; ++nt)
        pbf[cur ^ 1][nt] =
            *reinterpret_cast<const f16x8*>(pptr[nt] + (ks + 1) * 512);
    }
    f16x8 paf[2];
    #pragma unroll
    for (int mt = 0; mt < 2; ++mt)
      paf[mt] = *reinterpret_cast<const f16x8*>(
          &ao[wm * 32 + mt * 16 + l15][ks * 32 + g * 8]);
    #pragma unroll
    for (int mt = 0; mt < 2; ++mt)
      #pragma unroll
      for (int nt = 0; nt < 6; ++nt)
        pacc[mt][nt] = MFMA_F16(paf[mt], pbf[cur][nt], pacc[mt][nt]);
  }

  const size_t outbase = (size_t)b * kNTok * kC;
  #pragma unroll
  for (int mt = 0; mt < 2; ++mt) {
    #pragma unroll
    for (int j = 0; j < 4; ++j) {
      int r = wm * 32 + mt * 16 + g * 4 + j;
      int n = (wh * 8 + (r >> 3)) * 64 + ww * 8 + (r & 7);
      float* orow = out + outbase + (size_t)n * kC + wn * 96;
      #pragma unroll
      for (int nt = 0; nt < 6; ++nt) orow[nt * 16 + l15] = pacc[mt][nt][j];
    }
  }
}

// ===================== fallback path (round-3 kernel, verbatim) =====================

__global__ void prep_weights_fb(const float* __restrict__ Wqkv,
                                const float* __restrict__ Wproj,
                                f16* __restrict__ wq_pack,
                                f16* __restrict__ wp_pack) {
  int i = blockIdx.x * 256 + threadIdx.x;
  if (i < kQkvPackChunksFb) {
    int lane = i & 63;
    int chunk = i >> 6;
    int ks = chunk % 12;
    int t = (chunk / 12) % 12;
    int hp = chunk / 144;
    int l15 = lane & 15, g = lane >> 4;
    int base = t * 16;
    int hh = base / 96;
    int cc = base - hh * 96;
    int sec = cc >> 5;
    int dbhi = cc & 31;
    int n3 = sec * kC + (2 * hp + hh) * 32 + dbhi + l15;
    int k0 = ks * 32 + g * 8;
    f16x8 v;
    #pragma unroll
    for (int j = 0; j < 8; ++j)
      v[j] = (f16)Wqkv[(size_t)(k0 + j) * (3 * kC) + n3];
    *reinterpret_cast<f16x8*>(wq_pack + (size_t)i * 8) = v;
  } else if (i < kQkvPackChunksFb + kWpPackChunks) {
    int p = i - kQkvPackChunksFb;
    int lane = p & 63;
    int chunk = p >> 6;
    int ks = chunk % 12;
    int t = chunk / 12;
    int l15 = lane & 15, g = lane >> 4;
    int n = t * 16 + l15;
    int k0 = ks * 32 + g * 8;
    f16x8 v;
    #pragma unroll
    for (int j = 0; j < 8; ++j)
      v[j] = (f16)Wproj[(size_t)(k0 + j) * kC + n];
    *reinterpret_cast<f16x8*>(wp_pack + (size_t)p * 8) = v;
  }
}

__global__ __launch_bounds__(512, 2) void win_attn_fused_fb(
    const float* __restrict__ x, const float* __restrict__ b_qkv,
    const f16* __restrict__ wq_pack, const f16* __restrict__ wp_pack,
    float* __restrict__ out) {
  __shared__ alignas(16) f16 xs[64][392];
  __shared__ alignas(16) f16 ao[64][392];
  __shared__ alignas(16) f16 q_s[2][64][40];
  __shared__ alignas(16) f16 k_s[2][64][40];
  __shared__ alignas(16) f16 vT[2][32][72];
  __shared__ alignas(16) f16 p_s[8][16][72];

  const int tid = threadIdx.x;
  const int wid = tid >> 6;
  const int lane = tid & 63;
  const int g = lane >> 4;
  const int l15 = lane & 15;
  const int wm = wid >> 2;
  const int wn = wid & 3;

  const int blk = blockIdx.x;
  const int b = blk >> 6;
  const int win = blk & 63;
  const int wh = win >> 3;
  const int ww = win & 7;

  const f32x4 zero4 = {0.f, 0.f, 0.f, 0.f};

  {
    const float* xb = x + (size_t)b * kNTok * kC;
    #pragma unroll
    for (int it = 0; it < 12; ++it) {
      int idx = tid + it * 512;
      int r = idx / 96;
      int c4 = idx - r * 96;
      int n = (wh * 8 + (r >> 3)) * 64 + ww * 8 + (r & 7);
      float4 v = *reinterpret_cast<const float4*>(xb + (size_t)n * kC + c4 * 4);
      f16x4 hv = {(f16)v.x, (f16)v.y, (f16)v.z, (f16)v.w};
      *reinterpret_cast<f16x4*>(&xs[r][c4 * 4]) = hv;
    }
  }
  __syncthreads();

  for (int hp = 0; hp < 6; ++hp) {
    f32x4 acc[2][3];
    #pragma unroll
    for (int mt = 0; mt < 2; ++mt)
      #pragma unroll
      for (int nt = 0; nt < 3; ++nt) acc[mt][nt] = zero4;

    const f16* bptr[3];
    int secv[3], dbv[3], hhv[3];
    #pragma unroll
    for (int nt = 0; nt < 3; ++nt) {
      int t = wn * 3 + nt;
      int base = t * 16;
      int hh = base / 96;
      int cc = base - hh * 96;
      hhv[nt] = hh;
      secv[nt] = cc >> 5;
      dbv[nt] = cc & 31;
      bptr[nt] = wq_pack + ((size_t)((hp * 12 + t) * 12) * 64 + lane) * 8;
    }

    f16x8 bf[4][3];
    f16x8 af[2][2];
    #pragma unroll
    for (int p = 0; p < 3; ++p)
      #pragma unroll
      for (int nt = 0; nt < 3; ++nt)
        bf[p][nt] = *reinterpret_cast<const f16x8*>(bptr[nt] + p * 512);
    #pragma unroll
    for (int mt = 0; mt < 2; ++mt)
      af[0][mt] = *reinterpret_cast<const f16x8*>(
          &xs[wm * 32 + mt * 16 + l15][g * 8]);

    #pragma unroll
    for (int ks = 0; ks < 12; ++ks) {
      const int cur = ks & 3;
      const int ca = ks & 1;
      if (ks < 9) {
        const int nx = (ks + 3) & 3;
        #pragma unroll
        for (int nt = 0; nt < 3; ++nt)
          bf[nx][nt] =
              *reinterpret_cast<const f16x8*>(bptr[nt] + (ks + 3) * 512);
      }
      if (ks < 11) {
        #pragma unroll
        for (int mt = 0; mt < 2; ++mt)
          af[ca ^ 1][mt] = *reinterpret_cast<const f16x8*>(
              &xs[wm * 32 + mt * 16 + l15][(ks + 1) * 32 + g * 8]);
      }
      #pragma unroll
      for (int mt = 0; mt < 2; ++mt)
        #pragma unroll
        for (int nt = 0; nt < 3; ++nt)
          acc[mt][nt] = MFMA_F16(af[ca][mt], bf[cur][nt], acc[mt][nt]);
    }

    #pragma unroll
    for (int nt = 0; nt < 3; ++nt) {
      int hh = hhv[nt], sec = secv[nt];
      int col = dbv[nt] + l15;
      float bias = b_qkv[sec * kC + (2 * hp + hh) * 32 + col];
      #pragma unroll
      for (int mt = 0; mt < 2; ++mt) {
        #pragma unroll
        for (int j = 0; j < 4; ++j) {
          int r = wm * 32 + mt * 16 + g * 4 + j;
          f16 hv = (f16)(acc[mt][nt][j] + bias);
          if (sec == 0) q_s[hh][r][col] = hv;
          else if (sec == 1) k_s[hh][r][col] = hv;
          else vT[hh][col][r] = hv;
        }
      }
    }
    __syncthreads();

    f32x4 sacc[4];
    #pragma unroll
    for (int nt = 0; nt < 4; ++nt) sacc[nt] = zero4;
    f16x8 qa = *reinterpret_cast<const f16x8*>(&q_s[wm][wn * 16 + l15][g * 8]);
    #pragma unroll
    for (int nt = 0; nt < 4; ++nt) {
      f16x8 kb =
          *reinterpret_cast<const f16x8*>(&k_s[wm][nt * 16 + l15][g * 8]);
      sacc[nt] = MFMA_F16(qa, kb, sacc[nt]);
    }

    float pv[4][4];
    #pragma unroll
    for (int j = 0; j < 4; ++j) {
      float m = -1e30f;
      #pragma unroll
      for (int nt = 0; nt < 4; ++nt) {
        pv[nt][j] = sacc[nt][j] * kScale;
        m = fmaxf(m, pv[nt][j]);
      }
      m = fmaxf(m, __shfl_xor(m, 1));
      m = fmaxf(m, __shfl_xor(m, 2));
      m = fmaxf(m, __shfl_xor(m, 4));
      m = fmaxf(m, __shfl_xor(m, 8));
      float s = 0.f;
      #pragma unroll
      for (int nt = 0; nt < 4; ++nt) {
        pv[nt][j] = __expf(pv[nt][j] - m);
        s += pv[nt][j];
      }
      s += __shfl_xor(s, 1);
      s += __shfl_xor(s, 2);
      s += __shfl_xor(s, 4);
      s += __shfl_xor(s, 8);
      float inv = 1.0f / s;
      #pragma unroll
      for (int nt = 0; nt < 4; ++nt)
        p_s[wid][g * 4 + j][nt * 16 + l15] = (f16)(pv[nt][j] * inv);
    }

    f32x4 oacc[2];
    oacc[0] = zero4;
    oacc[1] = zero4;
    #pragma unroll
    for (int ks = 0; ks < 2; ++ks) {
      f16x8 pa =
          *reinterpret_cast<const f16x8*>(&p_s[wid][l15][ks * 32 + g * 8]);
      #pragma unroll
      for (int nt = 0; nt < 2; ++nt) {
        f16x8 vb = *reinterpret_cast<const f16x8*>(
            &vT[wm][nt * 16 + l15][ks * 32 + g * 8]);
        oacc[nt] = MFMA_F16(pa, vb, oacc[nt]);
      }
    }
    #pragma unroll
    for (int nt = 0; nt < 2; ++nt)
      #pragma unroll
      for (int j = 0; j < 4; ++j)
        ao[wn * 16 + g * 4 + j][(2 * hp + wm) * 32 + nt * 16 + l15] =
            (f16)oacc[nt][j];
    __syncthreads();
  }

  f32x4 pacc[2][6];
  #pragma unroll
  for (int mt = 0; mt < 2; ++mt)
    #pragma unroll
    for (int nt = 0; nt < 6; ++nt) pacc[mt][nt] = zero4;

  const f16* pptr[6];
  #pragma unroll
  for (int nt = 0; nt < 6; ++nt) {
    int t = wn * 6 + nt;
    pptr[nt] = wp_pack + ((size_t)(t * 12) * 64 + lane) * 8;
  }
  f16x8 pbf[3][6];
  f16x8 paf[2][2];
  #pragma unroll
  for (int p = 0; p < 2; ++p)
    #pragma unroll
    for (int nt = 0; nt < 6; ++nt)
      pbf[p][nt] = *reinterpret_cast<const f16x8*>(pptr[nt] + p * 512);
  #pragma unroll
  for (int mt = 0; mt < 2; ++mt)
    paf[0][mt] =
        *reinterpret_cast<const f16x8*>(&ao[wm * 32 + mt * 16 + l15][g * 8]);

  #pragma unroll
  for (int ks = 0; ks < 12; ++ks) {
    const int cur = ks % 3;
    const int ca = ks & 1;
    if (ks < 10) {
      const int nx = (ks + 2) % 3;
      #pragma unroll
      for (int nt = 0; nt < 6; ++nt)
        pbf[nx][nt] =
            *reinterpret_cast<const f16x8*>(pptr[nt] + (ks + 2) * 512);
    }
    if (ks < 11) {
      #pragma unroll
      for (int mt = 0; mt < 2; ++mt)
        paf[ca ^ 1][mt] = *reinterpret_cast<const f16x8*>(
            &ao[wm * 32 + mt * 16 + l15][(ks + 1) * 32 + g * 8]);
    }
    #pragma unroll
    for (int mt = 0; mt < 2; ++mt)
      #pragma unroll
      for (int nt = 0; nt < 6; ++nt)
        pacc[mt][nt] = MFMA_F16(paf[ca][mt], pbf[cur][nt], pacc[mt][nt]);
  }

  const size_t outbase = (size_t)b * kNTok * kC;
  #pragma unroll
  for (int mt = 0; mt < 2; ++mt) {
    #pragma unroll
    for (int j = 0; j < 4; ++j) {
      int r = wm * 32 + mt * 16 + g * 4 + j;
      int n = (wh * 8 + (r >> 3)) * 64 + ww * 8 + (r & 7);
      float* orow = out + outbase + (size_t)n * kC + wn * 96;
      #pragma unroll
      for (int nt = 0; nt < 6; ++nt) orow[nt * 16 + l15] = pacc[mt][nt][j];
    }
  }
}

// ===================== launch =====================

extern "C" void kernel_launch(void* const* d_in, const int* in_sizes, int n_in,
                              void* d_out, int out_size, void* d_ws,
                              size_t ws_size, hipStream_t stream) {
  const float* x = (const float*)d_in[0];
  const float* Wqkv = (const float*)d_in[1];
  const float* bqkv = (const float*)d_in[2];
  const float* Wproj = (const float*)d_in[3];
  float* out = (float*)d_out;

  if (ws_size >= kWsNeed) {
    f16* wq_pack = (f16*)d_ws;
    f16* wp_pack = (f16*)((char*)d_ws + kWqPackBytes);
    f16* qkv_ws = (f16*)((char*)d_ws + kWqPackBytes + kWpPackBytes);
    int prep_threads = kWqPackChunks + kWpPackChunks;  // 73728
    hipLaunchKernelGGL(prep_weights_split, dim3((prep_threads + 255) / 256),
                       dim3(256), 0, stream, Wqkv, Wproj, wq_pack, wp_pack);
    hipLaunchKernelGGL(qkv_gemm, dim3(512 * 9), dim3(256), 0, stream, x, bqkv,
                       wq_pack, qkv_ws);
    hipLaunchKernelGGL(attn_proj, dim3(16 * 64), dim3(512), 0, stream, qkv_ws,
                       wp_pack, out);
  } else {
    f16* wq_pack = (f16*)d_ws;
    f16* wp_pack = (f16*)((char*)d_ws + (size_t)kQkvPackChunksFb * 16);
    int prep_threads = kQkvPackChunksFb + kWpPackChunks;
    hipLaunchKernelGGL(prep_weights_fb, dim3((prep_threads + 255) / 256),
                       dim3(256), 0, stream, Wqkv, Wproj, wq_pack, wp_pack);
    hipLaunchKernelGGL(win_attn_fused_fb, dim3(16 * 64), dim3(512), 0, stream,
                       x, bqkv, wq_pack, wp_pack, out);
  }
}

// Round 5
// 173.895 us; speedup vs baseline: 2.4299x; 1.3611x over previous
//
#include <hip/hip_runtime.h>
#include <hip/hip_bf16.h>

// WindowAttention for MI355X (gfx950) — round 5.
// K1 rebuilt as a T3/T4 counted-vmcnt pipeline (3 LDS buffers, global_load_lds
// for A and B, raw s_barrier, vmcnt(8) steady state — never drained in-loop).
// x is pre-converted to f16 and packed in A-fragment order by prep_x (stored
// in d_out-as-scratch, overwritten later by the real output). K1 epilogue
// stores via an LDS re-order -> coalesced 1KB wave stores.

typedef _Float16 f16;
typedef f16 f16x8 __attribute__((ext_vector_type(8)));
typedef f16 f16x4 __attribute__((ext_vector_type(4)));
typedef float f32x4 __attribute__((ext_vector_type(4)));

#define MFMA_F16(a, b, c) __builtin_amdgcn_mfma_f32_16x16x32_f16((a), (b), (c), 0, 0, 0)

#define AS_G __attribute__((address_space(1)))
#define AS_L __attribute__((address_space(3)))
#define GLOAD_LDS16(gp, lp) \
  __builtin_amdgcn_global_load_lds((const AS_G void*)(gp), (AS_L void*)(lp), 16, 0, 0)
#define WAITVM_(N) asm volatile("s_waitcnt vmcnt(" #N ")" ::: "memory")
#define WAITVM(N) WAITVM_(N)

namespace {
constexpr int kC = 384;
constexpr int kNTok = 4096;
constexpr float kScale = 0.17677669529663687f;  // 1/sqrt(32)
constexpr int kWqPackChunks = 72 * 12 * 64;     // 55296 x 16B
constexpr int kWpPackChunks = 24 * 12 * 64;     // 18432 x 16B
constexpr size_t kWqPackBytes = (size_t)kWqPackChunks * 16;  // 884736
constexpr size_t kWpPackBytes = (size_t)kWpPackChunks * 16;  // 294912
constexpr size_t kQkvWsBytes = (size_t)65536 * 1152 * 2;     // 150994944
constexpr size_t kWsNeed = kWqPackBytes + kWpPackBytes + kQkvWsBytes;
constexpr int kQkvPackChunksFb = 6 * 12 * 12 * 64;  // fallback layout
}

// ===================== split path =====================

// pack Wqkv/Wproj f16 in B-fragment order: chunk=(t*12+ks), lane=g*16+l15,
// elem j = W[ks*32+g*8+j][t*16+l15]
__global__ void prep_weights_split(const float* __restrict__ Wqkv,
                                   const float* __restrict__ Wproj,
                                   f16* __restrict__ wq_pack,
                                   f16* __restrict__ wp_pack) {
  int i = blockIdx.x * 256 + threadIdx.x;
  if (i < kWqPackChunks) {
    int lane = i & 63;
    int chunk = i >> 6;
    int ks = chunk % 12;
    int t = chunk / 12;
    int l15 = lane & 15, g = lane >> 4;
    int n3 = t * 16 + l15;
    int k0 = ks * 32 + g * 8;
    f16x8 v;
    #pragma unroll
    for (int j = 0; j < 8; ++j)
      v[j] = (f16)Wqkv[(size_t)(k0 + j) * (3 * kC) + n3];
    *reinterpret_cast<f16x8*>(wq_pack + (size_t)i * 8) = v;
  } else if (i < kWqPackChunks + kWpPackChunks) {
    int p = i - kWqPackChunks;
    int lane = p & 63;
    int chunk = p >> 6;
    int ks = chunk % 12;
    int t = chunk / 12;
    int l15 = lane & 15, g = lane >> 4;
    int n = t * 16 + l15;
    int k0 = ks * 32 + g * 8;
    f16x8 v;
    #pragma unroll
    for (int j = 0; j < 8; ++j)
      v[j] = (f16)Wproj[(size_t)(k0 + j) * kC + n];
    *reinterpret_cast<f16x8*>(wp_pack + (size_t)p * 8) = v;
  }
}

// prep_x: x f32 -> f16, window-permuted AND A-fragment-packed.
// chunk c = (mb*12 + ks)*64 + lane; frag row = mb*16 + (lane&15) in
// (b,win,tok) order; elems k = ks*32 + (lane>>4)*8 + j.
__global__ void prep_x(const float* __restrict__ x, f16* __restrict__ xw) {
  int c = blockIdx.x * 256 + threadIdx.x;  // < 4096*12*64
  int lane = c & 63;
  int t = c >> 6;
  int ks = t % 12;
  int mb = t / 12;
  int l15 = lane & 15, g = lane >> 4;
  int m = mb * 16 + l15;
  int b = m >> 12;
  int win = (m >> 6) & 63;
  int tok = m & 63;
  int n = ((win >> 3) * 8 + (tok >> 3)) * 64 + (win & 7) * 8 + (tok & 7);
  const float* src = x + ((size_t)(b << 12) + n) * kC + ks * 32 + g * 8;
  float4 v0 = *reinterpret_cast<const float4*>(src);
  float4 v1 = *reinterpret_cast<const float4*>(src + 4);
  f16x8 h = {(f16)v0.x, (f16)v0.y, (f16)v0.z, (f16)v0.w,
             (f16)v1.x, (f16)v1.y, (f16)v1.z, (f16)v1.w};
  *reinterpret_cast<f16x8*>(xw + (size_t)c * 8) = h;
}

// K1: qkv = xw @ Wqkv + b. 128x128 tile, K=384 (12 steps), 3-buffer
// counted-vmcnt pipeline. Output packed [b*64+win][h*3+sec][tok][d] f16.
__global__ __launch_bounds__(256, 3) void qkv_gemm2(
    const f16* __restrict__ xw, const float* __restrict__ b_qkv,
    const f16* __restrict__ wq_pack, f16* __restrict__ qkv_ws) {
  // 3 bufs x (A 8KB + B 8KB) = 48 KB; epilogue reuses first 32 KB.
  __shared__ alignas(1024) char smem[49152];

  const int tid = threadIdx.x;
  const int wid = tid >> 6;
  const int lane = tid & 63;
  const int g = lane >> 4;
  const int l15 = lane & 15;
  const int wm = wid >> 1;
  const int wn = wid & 1;

  // XCD swizzle: 4608 = 8*576; n-major within XCD -> A-panel L2 reuse.
  int bid = blockIdx.x;
  int wg = (bid & 7) * 576 + (bid >> 3);
  int m_grp = wg / 9;        // [0,512)
  int n_grp = wg - m_grp * 9;
  const int mb0 = m_grp * 8;  // 16-row frag blocks
  const int nb0 = n_grp * 8;  // 16-col frag tiles

  // stage macro: 4 global_load_lds (A:2, B:2), 16B each, LDS dest linear.
  #define STAGE(KS, BUF)                                                     \
    do {                                                                     \
      const f16* ga0 = xw + (((size_t)(mb0 + wid) * 12 + (KS)) * 64 + lane) * 8;     \
      const f16* ga1 = xw + (((size_t)(mb0 + 4 + wid) * 12 + (KS)) * 64 + lane) * 8; \
      const f16* gb0 =                                                       \
          wq_pack + (((size_t)(nb0 + wid) * 12 + (KS)) * 64 + lane) * 8;     \
      const f16* gb1 =                                                       \
          wq_pack + (((size_t)(nb0 + 4 + wid) * 12 + (KS)) * 64 + lane) * 8; \
      char* la = smem + (BUF) * 16384 + wid * 1024;                          \
      char* lb = smem + (BUF) * 16384 + 8192 + wid * 1024;                   \
      GLOAD_LDS16(ga0, la);                                                  \
      GLOAD_LDS16(ga1, la + 4096);                                           \
      GLOAD_LDS16(gb0, lb);                                                  \
      GLOAD_LDS16(gb1, lb + 4096);                                           \
    } while (0)

  f32x4 acc[4][4];
  #pragma unroll
  for (int mt = 0; mt < 4; ++mt)
    #pragma unroll
    for (int nt = 0; nt < 4; ++nt) acc[mt][nt] = {0.f, 0.f, 0.f, 0.f};

  // prologue: stage ks=0,1,2
  STAGE(0, 0);
  STAGE(1, 1);
  STAGE(2, 2);
  WAITVM(8);  // stage0 done (2 stages = 8 instrs outstanding)
  __builtin_amdgcn_sched_barrier(0);
  __builtin_amdgcn_s_barrier();

  // loop iteration: read frags; barrier; restage same buf (ks+3); MFMA;
  // counted vmcnt (stage ks+1 done) + barrier.
  #define KITER(T, ENDVM)                                                    \
    do {                                                                     \
      constexpr int buf = (T) % 3;                                           \
      f16x8 af[4], bf[4];                                                    \
      _Pragma("unroll") for (int mt = 0; mt < 4; ++mt) af[mt] =              \
          *reinterpret_cast<const f16x8*>(smem + buf * 16384 +               \
                                          (wm * 4 + mt) * 1024 + lane * 16); \
      _Pragma("unroll") for (int nt = 0; nt < 4; ++nt) bf[nt] =              \
          *reinterpret_cast<const f16x8*>(smem + buf * 16384 + 8192 +        \
                                          (wn * 4 + nt) * 1024 + lane * 16); \
      asm volatile("s_waitcnt lgkmcnt(0)" ::: "memory");                     \
      __builtin_amdgcn_sched_barrier(0);                                     \
      __builtin_amdgcn_s_barrier();                                          \
      if ((T) < 9) {                                                         \
        STAGE((T) + 3, buf);                                                 \
      }                                                                      \
      __builtin_amdgcn_s_setprio(1);                                         \
      _Pragma("unroll") for (int mt = 0; mt < 4; ++mt)                       \
          _Pragma("unroll") for (int nt = 0; nt < 4; ++nt) acc[mt][nt] =     \
          MFMA_F16(af[mt], bf[nt], acc[mt][nt]);                             \
      __builtin_amdgcn_s_setprio(0);                                         \
      WAITVM(ENDVM);                                                         \
      __builtin_amdgcn_sched_barrier(0);                                     \
      __builtin_amdgcn_s_barrier();                                          \
    } while (0)

  KITER(0, 8);
  KITER(1, 8);
  KITER(2, 8);
  KITER(3, 8);
  KITER(4, 8);
  KITER(5, 8);
  KITER(6, 8);
  KITER(7, 8);
  KITER(8, 8);
  KITER(9, 4);
  KITER(10, 0);
  KITER(11, 0);
  #undef KITER
  #undef STAGE

  // ---- epilogue: bias, LDS re-order, coalesced stores ----
  f16* eo = (f16*)smem;  // [win_loc(2)][hsec_loc(4)][tok(64)][d(32)] = 32 KB
  #pragma unroll
  for (int nt = 0; nt < 4; ++nt) {
    int col128 = wn * 64 + nt * 16 + l15;
    float bias = b_qkv[n_grp * 128 + col128];
    int hsec_loc = col128 >> 5;
    int d = col128 & 31;
    #pragma unroll
    for (int mt = 0; mt < 4; ++mt) {
      #pragma unroll
      for (int j = 0; j < 4; ++j) {
        int tok = mt * 16 + g * 4 + j;
        eo[(((wm * 4 + hsec_loc) * 64) + tok) * 32 + d] =
            (f16)(acc[mt][nt][j] + bias);
      }
    }
  }
  __syncthreads();
  // copy out: 2048 x 16B units, unit u -> (win_loc, cb, inner)
  #pragma unroll
  for (int i = 0; i < 8; ++i) {
    int u = tid + i * 256;
    int win_loc = u >> 10;
    int cbl = (u >> 8) & 3;
    int inner = u & 255;
    int cb = n_grp * 4 + cbl;  // qkv column-block = sec*12 + h
    int h = cb % 12;
    int sec = cb / 12;
    size_t dst = ((size_t)(m_grp * 2 + win_loc) * 36 + h * 3 + sec) * 2048 +
                 (size_t)inner * 8;
    *reinterpret_cast<f16x8*>(qkv_ws + dst) =
        *reinterpret_cast<const f16x8*>(eo + (size_t)u * 8);
  }
}

// K2: attention + proj per window (unchanged from round 4)
__global__ __launch_bounds__(512, 4) void attn_proj(
    const f16* __restrict__ qkv_ws, const f16* __restrict__ wp_pack,
    float* __restrict__ out) {
  // LDS: 50176 + 9216 + 18432 = 77824 B -> 2 blocks/CU
  __shared__ alignas(16) f16 ao[64][392];
  __shared__ alignas(16) f16 vT[2][32][72];
  __shared__ alignas(16) f16 p_s[8][16][72];

  const int tid = threadIdx.x;
  const int wid = tid >> 6;
  const int lane = tid & 63;
  const int g = lane >> 4;
  const int l15 = lane & 15;
  const int wm = wid >> 2;
  const int wn = wid & 3;

  const int blk = blockIdx.x;
  const int b = blk >> 6;
  const int win = blk & 63;
  const int wh = win >> 3;
  const int ww = win & 7;

  const f32x4 zero4 = {0.f, 0.f, 0.f, 0.f};
  const f16* qkvb = qkv_ws + (size_t)(b * 64 + win) * 36 * 2048;

  const int v_hh = tid >> 8;
  const int v_tok = (tid >> 2) & 63;
  const int v_d0 = (tid & 3) * 8;

  for (int hp = 0; hp < 6; ++hp) {
    {
      int h2 = 2 * hp + v_hh;
      f16x8 v = *reinterpret_cast<const f16x8*>(
          qkvb + ((size_t)(h2 * 3 + 2) * 64 + v_tok) * 32 + v_d0);
      #pragma unroll
      for (int j = 0; j < 8; ++j) vT[v_hh][v_d0 + j][v_tok] = v[j];
    }
    __syncthreads();

    const int h = 2 * hp + wm;
    const f16* hb = qkvb + (size_t)h * 3 * 2048;
    f16x8 qa =
        *reinterpret_cast<const f16x8*>(hb + (wn * 16 + l15) * 32 + g * 8);
    f32x4 sacc[4];
    #pragma unroll
    for (int nt = 0; nt < 4; ++nt) sacc[nt] = zero4;
    #pragma unroll
    for (int nt = 0; nt < 4; ++nt) {
      f16x8 kb = *reinterpret_cast<const f16x8*>(
          hb + 2048 + (nt * 16 + l15) * 32 + g * 8);
      sacc[nt] = MFMA_F16(qa, kb, sacc[nt]);
    }

    float pv[4][4];
    #pragma unroll
    for (int j = 0; j < 4; ++j) {
      float m = -1e30f;
      #pragma unroll
      for (int nt = 0; nt < 4; ++nt) {
        pv[nt][j] = sacc[nt][j] * kScale;
        m = fmaxf(m, pv[nt][j]);
      }
      m = fmaxf(m, __shfl_xor(m, 1));
      m = fmaxf(m, __shfl_xor(m, 2));
      m = fmaxf(m, __shfl_xor(m, 4));
      m = fmaxf(m, __shfl_xor(m, 8));
      float s = 0.f;
      #pragma unroll
      for (int nt = 0; nt < 4; ++nt) {
        pv[nt][j] = __expf(pv[nt][j] - m);
        s += pv[nt][j];
      }
      s += __shfl_xor(s, 1);
      s += __shfl_xor(s, 2);
      s += __shfl_xor(s, 4);
      s += __shfl_xor(s, 8);
      float inv = 1.0f / s;
      #pragma unroll
      for (int nt = 0; nt < 4; ++nt)
        p_s[wid][g * 4 + j][nt * 16 + l15] = (f16)(pv[nt][j] * inv);
    }
    // no barrier: p_s[wid] wave-private

    f32x4 oacc[2];
    oacc[0] = zero4;
    oacc[1] = zero4;
    #pragma unroll
    for (int ks = 0; ks < 2; ++ks) {
      f16x8 pa =
          *reinterpret_cast<const f16x8*>(&p_s[wid][l15][ks * 32 + g * 8]);
      #pragma unroll
      for (int nt = 0; nt < 2; ++nt) {
        f16x8 vb = *reinterpret_cast<const f16x8*>(
            &vT[wm][nt * 16 + l15][ks * 32 + g * 8]);
        oacc[nt] = MFMA_F16(pa, vb, oacc[nt]);
      }
    }
    #pragma unroll
    for (int nt = 0; nt < 2; ++nt)
      #pragma unroll
      for (int j = 0; j < 4; ++j)
        ao[wn * 16 + g * 4 + j][h * 32 + nt * 16 + l15] = (f16)oacc[nt][j];
    __syncthreads();
  }

  f32x4 pacc[2][6];
  #pragma unroll
  for (int mt = 0; mt < 2; ++mt)
    #pragma unroll
    for (int nt = 0; nt < 6; ++nt) pacc[mt][nt] = zero4;

  const f16* pptr[6];
  #pragma unroll
  for (int nt = 0; nt < 6; ++nt) {
    int t = wn * 6 + nt;
    pptr[nt] = wp_pack + ((size_t)(t * 12) * 64 + lane) * 8;
  }
  f16x8 pbf[2][6];
  #pragma unroll
  for (int nt = 0; nt < 6; ++nt)
    pbf[0][nt] = *reinterpret_cast<const f16x8*>(pptr[nt]);

  #pragma unroll
  for (int ks = 0; ks < 12; ++ks) {
    const int cur = ks & 1;
    if (ks < 11) {
      #pragma unroll
      for (int nt = 0; nt < 6; ++nt)
        pbf[cur ^ 1][nt] =
            *reinterpret_cast<const f16x8*>(pptr[nt] + (ks + 1) * 512);
    }
    f16x8 paf[2];
    #pragma unroll
    for (int mt = 0; mt < 2; ++mt)
      paf[mt] = *reinterpret_cast<const f16x8*>(
          &ao[wm * 32 + mt * 16 + l15][ks * 32 + g * 8]);
    #pragma unroll
    for (int mt = 0; mt < 2; ++mt)
      #pragma unroll
      for (int nt = 0; nt < 6; ++nt)
        pacc[mt][nt] = MFMA_F16(paf[mt], pbf[cur][nt], pacc[mt][nt]);
  }

  const size_t outbase = (size_t)b * kNTok * kC;
  #pragma unroll
  for (int mt = 0; mt < 2; ++mt) {
    #pragma unroll
    for (int j = 0; j < 4; ++j) {
      int r = wm * 32 + mt * 16 + g * 4 + j;
      int n = (wh * 8 + (r >> 3)) * 64 + ww * 8 + (r & 7);
      float* orow = out + outbase + (size_t)n * kC + wn * 96;
      #pragma unroll
      for (int nt = 0; nt < 6; ++nt) orow[nt * 16 + l15] = pacc[mt][nt][j];
    }
  }
}

// ===================== fallback path (round-3 fused kernel) =====================

__global__ void prep_weights_fb(const float* __restrict__ Wqkv,
                                const float* __restrict__ Wproj,
                                f16* __restrict__ wq_pack,
                                f16* __restrict__ wp_pack) {
  int i = blockIdx.x * 256 + threadIdx.x;
  if (i < kQkvPackChunksFb) {
    int lane = i & 63;
    int chunk = i >> 6;
    int ks = chunk % 12;
    int t = (chunk / 12) % 12;
    int hp = chunk / 144;
    int l15 = lane & 15, g = lane >> 4;
    int base = t * 16;
    int hh = base / 96;
    int cc = base - hh * 96;
    int sec = cc >> 5;
    int dbhi = cc & 31;
    int n3 = sec * kC + (2 * hp + hh) * 32 + dbhi + l15;
    int k0 = ks * 32 + g * 8;
    f16x8 v;
    #pragma unroll
    for (int j = 0; j < 8; ++j)
      v[j] = (f16)Wqkv[(size_t)(k0 + j) * (3 * kC) + n3];
    *reinterpret_cast<f16x8*>(wq_pack + (size_t)i * 8) = v;
  } else if (i < kQkvPackChunksFb + kWpPackChunks) {
    int p = i - kQkvPackChunksFb;
    int lane = p & 63;
    int chunk = p >> 6;
    int ks = chunk % 12;
    int t = chunk / 12;
    int l15 = lane & 15, g = lane >> 4;
    int n = t * 16 + l15;
    int k0 = ks * 32 + g * 8;
    f16x8 v;
    #pragma unroll
    for (int j = 0; j < 8; ++j)
      v[j] = (f16)Wproj[(size_t)(k0 + j) * kC + n];
    *reinterpret_cast<f16x8*>(wp_pack + (size_t)p * 8) = v;
  }
}

__global__ __launch_bounds__(512, 2) void win_attn_fused_fb(
    const float* __restrict__ x, const float* __restrict__ b_qkv,
    const f16* __restrict__ wq_pack, const f16* __restrict__ wp_pack,
    float* __restrict__ out) {
  __shared__ alignas(16) f16 xs[64][392];
  __shared__ alignas(16) f16 ao[64][392];
  __shared__ alignas(16) f16 q_s[2][64][40];
  __shared__ alignas(16) f16 k_s[2][64][40];
  __shared__ alignas(16) f16 vT[2][32][72];
  __shared__ alignas(16) f16 p_s[8][16][72];

  const int tid = threadIdx.x;
  const int wid = tid >> 6;
  const int lane = tid & 63;
  const int g = lane >> 4;
  const int l15 = lane & 15;
  const int wm = wid >> 2;
  const int wn = wid & 3;

  const int blk = blockIdx.x;
  const int b = blk >> 6;
  const int win = blk & 63;
  const int wh = win >> 3;
  const int ww = win & 7;

  const f32x4 zero4 = {0.f, 0.f, 0.f, 0.f};

  {
    const float* xb = x + (size_t)b * kNTok * kC;
    #pragma unroll
    for (int it = 0; it < 12; ++it) {
      int idx = tid + it * 512;
      int r = idx / 96;
      int c4 = idx - r * 96;
      int n = (wh * 8 + (r >> 3)) * 64 + ww * 8 + (r & 7);
      float4 v = *reinterpret_cast<const float4*>(xb + (size_t)n * kC + c4 * 4);
      f16x4 hv = {(f16)v.x, (f16)v.y, (f16)v.z, (f16)v.w};
      *reinterpret_cast<f16x4*>(&xs[r][c4 * 4]) = hv;
    }
  }
  __syncthreads();

  for (int hp = 0; hp < 6; ++hp) {
    f32x4 acc[2][3];
    #pragma unroll
    for (int mt = 0; mt < 2; ++mt)
      #pragma unroll
      for (int nt = 0; nt < 3; ++nt) acc[mt][nt] = zero4;

    const f16* bptr[3];
    int secv[3], dbv[3], hhv[3];
    #pragma unroll
    for (int nt = 0; nt < 3; ++nt) {
      int t = wn * 3 + nt;
      int base = t * 16;
      int hh = base / 96;
      int cc = base - hh * 96;
      hhv[nt] = hh;
      secv[nt] = cc >> 5;
      dbv[nt] = cc & 31;
      bptr[nt] = wq_pack + ((size_t)((hp * 12 + t) * 12) * 64 + lane) * 8;
    }

    f16x8 bf[4][3];
    f16x8 af[2][2];
    #pragma unroll
    for (int p = 0; p < 3; ++p)
      #pragma unroll
      for (int nt = 0; nt < 3; ++nt)
        bf[p][nt] = *reinterpret_cast<const f16x8*>(bptr[nt] + p * 512);
    #pragma unroll
    for (int mt = 0; mt < 2; ++mt)
      af[0][mt] = *reinterpret_cast<const f16x8*>(
          &xs[wm * 32 + mt * 16 + l15][g * 8]);

    #pragma unroll
    for (int ks = 0; ks < 12; ++ks) {
      const int cur = ks & 3;
      const int ca = ks & 1;
      if (ks < 9) {
        const int nx = (ks + 3) & 3;
        #pragma unroll
        for (int nt = 0; nt < 3; ++nt)
          bf[nx][nt] =
              *reinterpret_cast<const f16x8*>(bptr[nt] + (ks + 3) * 512);
      }
      if (ks < 11) {
        #pragma unroll
        for (int mt = 0; mt < 2; ++mt)
          af[ca ^ 1][mt] = *reinterpret_cast<const f16x8*>(
              &xs[wm * 32 + mt * 16 + l15][(ks + 1) * 32 + g * 8]);
      }
      #pragma unroll
      for (int mt = 0; mt < 2; ++mt)
        #pragma unroll
        for (int nt = 0; nt < 3; ++nt)
          acc[mt][nt] = MFMA_F16(af[ca][mt], bf[cur][nt], acc[mt][nt]);
    }

    #pragma unroll
    for (int nt = 0; nt < 3; ++nt) {
      int hh = hhv[nt], sec = secv[nt];
      int col = dbv[nt] + l15;
      float bias = b_qkv[sec * kC + (2 * hp + hh) * 32 + col];
      #pragma unroll
      for (int mt = 0; mt < 2; ++mt) {
        #pragma unroll
        for (int j = 0; j < 4; ++j) {
          int r = wm * 32 + mt * 16 + g * 4 + j;
          f16 hv = (f16)(acc[mt][nt][j] + bias);
          if (sec == 0) q_s[hh][r][col] = hv;
          else if (sec == 1) k_s[hh][r][col] = hv;
          else vT[hh][col][r] = hv;
        }
      }
    }
    __syncthreads();

    f32x4 sacc[4];
    #pragma unroll
    for (int nt = 0; nt < 4; ++nt) sacc[nt] = zero4;
    f16x8 qa = *reinterpret_cast<const f16x8*>(&q_s[wm][wn * 16 + l15][g * 8]);
    #pragma unroll
    for (int nt = 0; nt < 4; ++nt) {
      f16x8 kb =
          *reinterpret_cast<const f16x8*>(&k_s[wm][nt * 16 + l15][g * 8]);
      sacc[nt] = MFMA_F16(qa, kb, sacc[nt]);
    }

    float pv[4][4];
    #pragma unroll
    for (int j = 0; j < 4; ++j) {
      float m = -1e30f;
      #pragma unroll
      for (int nt = 0; nt < 4; ++nt) {
        pv[nt][j] = sacc[nt][j] * kScale;
        m = fmaxf(m, pv[nt][j]);
      }
      m = fmaxf(m, __shfl_xor(m, 1));
      m = fmaxf(m, __shfl_xor(m, 2));
      m = fmaxf(m, __shfl_xor(m, 4));
      m = fmaxf(m, __shfl_xor(m, 8));
      float s = 0.f;
      #pragma unroll
      for (int nt = 0; nt < 4; ++nt) {
        pv[nt][j] = __expf(pv[nt][j] - m);
        s += pv[nt][j];
      }
      s += __shfl_xor(s, 1);
      s += __shfl_xor(s, 2);
      s += __shfl_xor(s, 4);
      s += __shfl_xor(s, 8);
      float inv = 1.0f / s;
      #pragma unroll
      for (int nt = 0; nt < 4; ++nt)
        p_s[wid][g * 4 + j][nt * 16 + l15] = (f16)(pv[nt][j] * inv);
    }

    f32x4 oacc[2];
    oacc[0] = zero4;
    oacc[1] = zero4;
    #pragma unroll
    for (int ks = 0; ks < 2; ++ks) {
      f16x8 pa =
          *reinterpret_cast<const f16x8*>(&p_s[wid][l15][ks * 32 + g * 8]);
      #pragma unroll
      for (int nt = 0; nt < 2; ++nt) {
        f16x8 vb = *reinterpret_cast<const f16x8*>(
            &vT[wm][nt * 16 + l15][ks * 32 + g * 8]);
        oacc[nt] = MFMA_F16(pa, vb, oacc[nt]);
      }
    }
    #pragma unroll
    for (int nt = 0; nt < 2; ++nt)
      #pragma unroll
      for (int j = 0; j < 4; ++j)
        ao[wn * 16 + g * 4 + j][(2 * hp + wm) * 32 + nt * 16 + l15] =
            (f16)oacc[nt][j];
    __syncthreads();
  }

  f32x4 pacc[2][6];
  #pragma unroll
  for (int mt = 0; mt < 2; ++mt)
    #pragma unroll
    for (int nt = 0; nt < 6; ++nt) pacc[mt][nt] = zero4;

  const f16* pptr[6];
  #pragma unroll
  for (int nt = 0; nt < 6; ++nt) {
    int t = wn * 6 + nt;
    pptr[nt] = wp_pack + ((size_t)(t * 12) * 64 + lane) * 8;
  }
  f16x8 pbf[3][6];
  f16x8 paf[2][2];
  #pragma unroll
  for (int p = 0; p < 2; ++p)
    #pragma unroll
    for (int nt = 0; nt < 6; ++nt)
      pbf[p][nt] = *reinterpret_cast<const f16x8*>(pptr[nt] + p * 512);
  #pragma unroll
  for (int mt = 0; mt < 2; ++mt)
    paf[0][mt] =
        *reinterpret_cast<const f16x8*>(&ao[wm * 32 + mt * 16 + l15][g * 8]);

  #pragma unroll
  for (int ks = 0; ks < 12; ++ks) {
    const int cur = ks % 3;
    const int ca = ks & 1;
    if (ks < 10) {
      const int nx = (ks + 2) % 3;
      #pragma unroll
      for (int nt = 0; nt < 6; ++nt)
        pbf[nx][nt] =
            *reinterpret_cast<const f16x8*>(pptr[nt] + (ks + 2) * 512);
    }
    if (ks < 11) {
      #pragma unroll
      for (int mt = 0; mt < 2; ++mt)
        paf[ca ^ 1][mt] = *reinterpret_cast<const f16x8*>(
            &ao[wm * 32 + mt * 16 + l15][(ks + 1) * 32 + g * 8]);
    }
    #pragma unroll
    for (int mt = 0; mt < 2; ++mt)
      #pragma unroll
      for (int nt = 0; nt < 6; ++nt)
        pacc[mt][nt] = MFMA_F16(paf[ca][mt], pbf[cur][nt], pacc[mt][nt]);
  }

  const size_t outbase = (size_t)b * kNTok * kC;
  #pragma unroll
  for (int mt = 0; mt < 2; ++mt) {
    #pragma unroll
    for (int j = 0; j < 4; ++j) {
      int r = wm * 32 + mt * 16 + g * 4 + j;
      int n = (wh * 8 + (r >> 3)) * 64 + ww * 8 + (r & 7);
      float* orow = out + outbase + (size_t)n * kC + wn * 96;
      #pragma unroll
      for (int nt = 0; nt < 6; ++nt) orow[nt * 16 + l15] = pacc[mt][nt][j];
    }
  }
}

// ===================== launch =====================

extern "C" void kernel_launch(void* const* d_in, const int* in_sizes, int n_in,
                              void* d_out, int out_size, void* d_ws,
                              size_t ws_size, hipStream_t stream) {
  const float* x = (const float*)d_in[0];
  const float* Wqkv = (const float*)d_in[1];
  const float* bqkv = (const float*)d_in[2];
  const float* Wproj = (const float*)d_in[3];
  float* out = (float*)d_out;

  if (ws_size >= kWsNeed) {
    f16* wq_pack = (f16*)d_ws;
    f16* wp_pack = (f16*)((char*)d_ws + kWqPackBytes);
    f16* qkv_ws = (f16*)((char*)d_ws + kWqPackBytes + kWpPackBytes);
    f16* xw = (f16*)d_out;  // 50 MB scratch inside the 100 MB output buffer

    int prep_threads = kWqPackChunks + kWpPackChunks;  // 73728
    hipLaunchKernelGGL(prep_weights_split, dim3((prep_threads + 255) / 256),
                       dim3(256), 0, stream, Wqkv, Wproj, wq_pack, wp_pack);
    hipLaunchKernelGGL(prep_x, dim3(12288), dim3(256), 0, stream, x, xw);
    hipLaunchKernelGGL(qkv_gemm2, dim3(4608), dim3(256), 0, stream, xw, bqkv,
                       wq_pack, qkv_ws);
    hipLaunchKernelGGL(attn_proj, dim3(16 * 64), dim3(512), 0, stream, qkv_ws,
                       wp_pack, out);
  } else {
    f16* wq_pack = (f16*)d_ws;
    f16* wp_pack = (f16*)((char*)d_ws + (size_t)kQkvPackChunksFb * 16);
    int prep_threads = kQkvPackChunksFb + kWpPackChunks;
    hipLaunchKernelGGL(prep_weights_fb, dim3((prep_threads + 255) / 256),
                       dim3(256), 0, stream, Wqkv, Wproj, wq_pack, wp_pack);
    hipLaunchKernelGGL(win_attn_fused_fb, dim3(16 * 64), dim3(512), 0, stream,
                       x, bqkv, wq_pack, wp_pack, out);
  }
}